// Round 15
// baseline (929.237 us; speedup 1.0000x reference)
//
#include <hip/hip_runtime.h>
#include <hip/hip_bf16.h>
#include <math.h>

#define N_NODES 100000
#define N_FEAT 500
#define N_HID 256
#define N_CLASS 40
#define NG 3125      // groups of 32 rows
#define CAP_G 1280   // per-group bucket capacity (mean 1024, std 32)

typedef float f32x4 __attribute__((ext_vector_type(4)));
typedef float f32x2 __attribute__((ext_vector_type(2)));
typedef int i32x4 __attribute__((ext_vector_type(4)));
typedef unsigned int u32x4 __attribute__((ext_vector_type(4)));
typedef short short8 __attribute__((ext_vector_type(8)));
typedef unsigned short u16x8 __attribute__((ext_vector_type(8)));

__device__ __forceinline__ float b2f(unsigned short u) {
  union { unsigned int i; float f; } c; c.i = ((unsigned int)u) << 16; return c.f;
}
__device__ __forceinline__ unsigned short f2bu(float x) {
  __hip_bfloat16 b = __float2bfloat16(x);
  union { __hip_bfloat16 b; unsigned short u; } c; c.b = b; return c.u;
}
__device__ __forceinline__ float decode_val(unsigned int p) {
  union { unsigned int i; float f; } c; c.i = (p & 0x7FFFu) << 17; return c.f;
}
__device__ __forceinline__ unsigned char f2fp8(float x) {
  return (unsigned char)(__builtin_amdgcn_cvt_pk_fp8_f32(x, x, 0, false) & 0xFF);
}
__device__ __forceinline__ void gload_lds16(const void* gptr, void* lptr) {
  __builtin_amdgcn_global_load_lds(
      (const __attribute__((address_space(1))) unsigned int*)gptr,
      (__attribute__((address_space(3))) unsigned int*)lptr, 16, 0, 0);
}

// ---------------------------------------------------------------------------
// prep (r12 exact): blocks 0..63 cast W1 -> W1Tsw bf16 swizzled; all blocks:
// histogram of er + pack cvps[i] = col<<15 | bf16(val)>>1, edge order.
// ---------------------------------------------------------------------------
__global__ __launch_bounds__(256) void prep_kernel(
    const float* __restrict__ W1, unsigned short* __restrict__ Bsw,
    const int* __restrict__ er, const int* __restrict__ ec,
    const float* __restrict__ ev, int* __restrict__ cnt,
    unsigned int* __restrict__ cvps, int E) {
  if (blockIdx.x < 64) {
    int t = blockIdx.x * 256 + threadIdx.x;
    int col = t >> 6, ch = t & 63;
    int g = ch >> 3, c = ch & 7;
    int c_src = c ^ (col & 7);
    int k = g * 64 + c_src * 8;
    u16x8 o;
#pragma unroll
    for (int j = 0; j < 8; j++) {
      int kk = k + j;
      o[j] = (kk < N_FEAT) ? f2bu(W1[(size_t)kk * N_HID + col]) : (unsigned short)0;
    }
    *(u16x8*)(Bsw + (size_t)col * 512 + g * 64 + c * 8) = o;
  }
  int nv = E >> 2;
  int t = blockIdx.x * 256 + threadIdx.x;
  int nthr = gridDim.x * 256;
  const i32x4* er4 = (const i32x4*)er;
  const i32x4* ec4 = (const i32x4*)ec;
  const f32x4* ev4 = (const f32x4*)ev;
  for (int i = t; i < nv; i += nthr) {
    i32x4 r = __builtin_nontemporal_load(&er4[i]);
    i32x4 c = __builtin_nontemporal_load(&ec4[i]);
    f32x4 v = __builtin_nontemporal_load(&ev4[i]);
    atomicAdd(&cnt[r.x], 1);
    atomicAdd(&cnt[r.y], 1);
    atomicAdd(&cnt[r.z], 1);
    atomicAdd(&cnt[r.w], 1);
    u32x4 pk;
    pk.x = ((unsigned int)c.x << 15) | ((unsigned int)f2bu(v.x) >> 1);
    pk.y = ((unsigned int)c.y << 15) | ((unsigned int)f2bu(v.y) >> 1);
    pk.z = ((unsigned int)c.z << 15) | ((unsigned int)f2bu(v.z) >> 1);
    pk.w = ((unsigned int)c.w << 15) | ((unsigned int)f2bu(v.w) >> 1);
    __builtin_nontemporal_store(pk, (u32x4*)(cvps + 4 * (size_t)i));
  }
  int tail = nv << 2;
  if (blockIdx.x == 0 && threadIdx.x < E - tail) {
    int i = tail + threadIdx.x;
    atomicAdd(&cnt[er[i]], 1);
    cvps[i] = ((unsigned int)ec[i] << 15) | ((unsigned int)f2bu(ev[i]) >> 1);
  }
}

// ---------------------------------------------------------------------------
// Phase A: bin edges into per-group buckets (g = row>>5). Sliced scan
// (slice = g&3) keeps each slice's ~780 active bucket lines in 1-2 L2s;
// bucket lines fill sequentially -> written back ~once (vs 16x churn of the
// direct row-scatter). Plain atomics only.
// ---------------------------------------------------------------------------
__global__ __launch_bounds__(256) void bin_kernel(
    const int* __restrict__ er, const unsigned int* __restrict__ cvps,
    int* __restrict__ gcur, unsigned long long* __restrict__ grec, int E) {
  int s = blockIdx.x & 3;
  int g = blockIdx.x >> 2;
  int ngrp = gridDim.x >> 2;
  int nv = E >> 2;
  const i32x4* er4 = (const i32x4*)er;
  const u32x4* cv4 = (const u32x4*)cvps;
  for (int i = g * 256 + threadIdx.x; i < nv; i += ngrp * 256) {
    i32x4 r = __builtin_nontemporal_load(&er4[i]);
    u32x4 p = __builtin_nontemporal_load(&cv4[i]);
#define BINW(RR, PP)                                                        \
    {                                                                       \
      int gg = (RR) >> 5;                                                   \
      if ((gg & 3) == s) {                                                  \
        int pos = atomicAdd(&gcur[gg], 1);                                  \
        if (pos < CAP_G)                                                    \
          grec[(size_t)gg * CAP_G + pos] =                                  \
              ((unsigned long long)(unsigned int)(RR) << 32) | (PP);        \
      }                                                                     \
    }
    BINW(r.x, p.x)
    BINW(r.y, p.y)
    BINW(r.z, p.z)
    BINW(r.w, p.w)
#undef BINW
  }
  int tail = nv << 2;
  if (blockIdx.x == 0 && threadIdx.x < E - tail) {
    int i = tail + threadIdx.x;
    int row = er[i];
    int gg = row >> 5;
    int pos = atomicAdd(&gcur[gg], 1);
    if (pos < CAP_G)
      grec[(size_t)gg * CAP_G + pos] =
          ((unsigned long long)(unsigned int)row << 32) | cvps[i];
  }
}

// ---------------------------------------------------------------------------
// Phase B: consume buckets -> final row-major cvp. Block owns 2 whole groups;
// destination is the groups' contiguous ~4 KB cvp windows (burst-written,
// L2-local). Cursor atomics touch only this block's 64 rows.
// ---------------------------------------------------------------------------
__global__ __launch_bounds__(256) void gather_kernel(
    const unsigned long long* __restrict__ grec, const int* __restrict__ gcur,
    int* __restrict__ cursor, unsigned int* __restrict__ cvp) {
  int g0 = blockIdx.x * 2;
#pragma unroll
  for (int j = 0; j < 2; j++) {
    int g = g0 + j;
    if (g >= NG) break;
    int n = gcur[g];
    if (n > CAP_G) n = CAP_G;
    const unsigned long long* B = grec + (size_t)g * CAP_G;
    for (int i = threadIdx.x; i < n; i += 256) {
      unsigned long long rec = B[i];
      int row = (int)(rec >> 32);
      int pos = atomicAdd(&cursor[row], 1);
      cvp[pos] = (unsigned int)rec;
    }
  }
}

// ---------------------------------------------------------------------------
// GEMM1 (bf16 MFMA, r12 exact): H[M,256] = A[M,500] @ W1 + b1, fp8 out.
// BM=32, BN=256, BK=64; 256 threads = 4 waves; 36 KB LDS.
// ---------------------------------------------------------------------------
__global__ __launch_bounds__(256) void gemm1_mfma(
    const float* __restrict__ A, const unsigned short* __restrict__ Bsw,
    const float* __restrict__ b1, unsigned char* __restrict__ H, int M) {
  __shared__ __align__(16) char smem[36864];
  char* sA = smem;            // [32 rows][128 B]
  char* sB = smem + 4096;     // [256 cols][128 B]
  int tid = threadIdx.x;
  int lane = tid & 63, w = tid >> 6;
  int wc = w;
  int bm = blockIdx.x * 32;

  f32x4 acc[2][4];
#pragma unroll
  for (int m = 0; m < 2; m++)
#pragma unroll
    for (int n = 0; n < 4; n++) acc[m][n] = (f32x4)0.f;

  for (int s = 0; s < 8; s++) {
    int k0 = s * 64;
#pragma unroll
    for (int i = 0; i < 2; i++) {
      int f4 = i * 256 + tid;
      int row = f4 >> 4, cidx = f4 & 15;
      int grow = bm + row;
      int k = k0 + cidx * 4;
      float4 v = make_float4(0.f, 0.f, 0.f, 0.f);
      if (grow < M && k < N_FEAT) v = *(const float4*)(A + (size_t)grow * N_FEAT + k);
      ushort4 u;
      u.x = f2bu(v.x); u.y = f2bu(v.y); u.z = f2bu(v.z); u.w = f2bu(v.w);
      int chunk = cidx >> 1, sub = cidx & 1;
      int byte = row * 128 + (((chunk ^ (row & 7))) << 4) + (sub << 3);
      *(ushort4*)(sA + byte) = u;
    }
#pragma unroll
    for (int j = 0; j < 8; j++) {
      int base = j * 4096 + w * 1024;
      int L = base + lane * 16;
      int col = L >> 7, c = (L >> 4) & 7;
      const char* g = (const char*)Bsw + (size_t)col * 1024 + s * 128 + c * 16;
      gload_lds16(g, sB + base);
    }
    __syncthreads();
#pragma unroll
    for (int kk = 0; kk < 2; kk++) {
      int cw = kk * 4 + (lane >> 4);
      short8 af[2], bg[4];
#pragma unroll
      for (int m = 0; m < 2; m++) {
        int ar = m * 16 + (lane & 15);
        af[m] = *(const short8*)(sA + ar * 128 + ((cw ^ (ar & 7)) << 4));
      }
#pragma unroll
      for (int n = 0; n < 4; n++) {
        int bc = wc * 64 + n * 16 + (lane & 15);
        bg[n] = *(const short8*)(sB + bc * 128 + ((cw ^ (bc & 7)) << 4));
      }
#pragma unroll
      for (int m = 0; m < 2; m++)
#pragma unroll
        for (int n = 0; n < 4; n++)
          acc[m][n] = __builtin_amdgcn_mfma_f32_16x16x32_bf16(af[m], bg[n], acc[m][n], 0, 0, 0);
    }
    __syncthreads();
  }

  float bias[4];
#pragma unroll
  for (int n = 0; n < 4; n++) bias[n] = b1[wc * 64 + n * 16 + (lane & 15)];
#pragma unroll
  for (int m = 0; m < 2; m++) {
#pragma unroll
    for (int r = 0; r < 4; r++) {
      int row = bm + m * 16 + ((lane >> 4) << 2) + r;
      if (row < M) {
#pragma unroll
        for (int n = 0; n < 4; n++) {
          int col = wc * 64 + n * 16 + (lane & 15);
          H[(size_t)row * N_HID + col] = f2fp8(acc[m][n][r] + bias[n]);
        }
      }
    }
  }
}

// ---------------------------------------------------------------------------
// scans (unchanged)
// ---------------------------------------------------------------------------
__global__ __launch_bounds__(1024) void scan1_kernel(
    int* __restrict__ cnt, int* __restrict__ bsum, int n) {
  __shared__ int wsum[16];
  int tid = threadIdx.x, lane = tid & 63, wid = tid >> 6;
  int i = blockIdx.x * 1024 + tid;
  int v = (i < n) ? cnt[i] : 0;
  int x = v;
#pragma unroll
  for (int off = 1; off < 64; off <<= 1) {
    int t = __shfl_up(x, off);
    if (lane >= off) x += t;
  }
  if (lane == 63) wsum[wid] = x;
  __syncthreads();
  if (tid < 16) {
    int ws = wsum[tid];
#pragma unroll
    for (int off = 1; off < 16; off <<= 1) {
      int t = __shfl_up(ws, off);
      if (tid >= off) ws += t;
    }
    wsum[tid] = ws;
  }
  __syncthreads();
  int excl = (wid ? wsum[wid - 1] : 0) + x - v;
  if (i < n) cnt[i] = excl;
  if (tid == 0) bsum[blockIdx.x] = wsum[15];
}

__global__ __launch_bounds__(64) void scan2_kernel(
    int* __restrict__ bsum, int* __restrict__ row_ptr, int nb, int n) {
  int lane = threadIdx.x;
  int carry = 0;
  for (int base = 0; base < nb; base += 64) {
    int i = base + lane;
    int v = (i < nb) ? bsum[i] : 0;
    int x = v;
#pragma unroll
    for (int off = 1; off < 64; off <<= 1) {
      int t = __shfl_up(x, off);
      if (lane >= off) x += t;
    }
    if (i < nb) bsum[i] = carry + x - v;
    carry += __shfl(x, 63);
  }
  if (lane == 0) row_ptr[n] = carry;
}

__global__ __launch_bounds__(256) void scan3_kernel(
    int* __restrict__ cnt, const int* __restrict__ bsum,
    int* __restrict__ row_ptr, int n) {
  int i = blockIdx.x * 256 + threadIdx.x;
  if (i >= n) return;
  int v = cnt[i] + bsum[i >> 10];
  cnt[i] = v;
  row_ptr[i] = v;
}

// ---------------------------------------------------------------------------
// SPMM1 (CSR, F=256, fp8 X -> bf16 Y, fused ReLU): wave per row, 4 edges per
// step (16-lane groups), 16 feats x 16 B gather per lane, HW fp8 decode.
// ---------------------------------------------------------------------------
__global__ __launch_bounds__(256) void spmm_fp8(
    const int* __restrict__ row_ptr, const unsigned int* __restrict__ cvp,
    const unsigned char* __restrict__ X, unsigned short* __restrict__ Y, int M) {
  int wave = (blockIdx.x * 256 + threadIdx.x) >> 6;
  int lane = threadIdx.x & 63;
  if (wave >= M) return;
  int start = row_ptr[wave], end = row_ptr[wave + 1];
  int qf = lane >> 4, fl = lane & 15;
  f32x4 a0 = (f32x4)0.f, a1 = (f32x4)0.f, a2 = (f32x4)0.f, a3 = (f32x4)0.f;
  const unsigned char* Xf = X + fl * 16;
#pragma unroll 2
  for (int e = start; e < end; e += 4) {
    int ei = e + qf;
    unsigned int p = (ei < end) ? cvp[ei] : 0u;
    float val = decode_val(p);
    size_t col = (size_t)(p >> 15);
    u32x4 d = *(const u32x4*)(Xf + col * N_HID);
    f32x2 f0 = __builtin_amdgcn_cvt_pk_f32_fp8(d.x, false);
    f32x2 f1 = __builtin_amdgcn_cvt_pk_f32_fp8(d.x, true);
    f32x2 f2 = __builtin_amdgcn_cvt_pk_f32_fp8(d.y, false);
    f32x2 f3 = __builtin_amdgcn_cvt_pk_f32_fp8(d.y, true);
    f32x2 f4 = __builtin_amdgcn_cvt_pk_f32_fp8(d.z, false);
    f32x2 f5 = __builtin_amdgcn_cvt_pk_f32_fp8(d.z, true);
    f32x2 f6 = __builtin_amdgcn_cvt_pk_f32_fp8(d.w, false);
    f32x2 f7 = __builtin_amdgcn_cvt_pk_f32_fp8(d.w, true);
    a0.x = fmaf(val, f0.x, a0.x); a0.y = fmaf(val, f0.y, a0.y);
    a0.z = fmaf(val, f1.x, a0.z); a0.w = fmaf(val, f1.y, a0.w);
    a1.x = fmaf(val, f2.x, a1.x); a1.y = fmaf(val, f2.y, a1.y);
    a1.z = fmaf(val, f3.x, a1.z); a1.w = fmaf(val, f3.y, a1.w);
    a2.x = fmaf(val, f4.x, a2.x); a2.y = fmaf(val, f4.y, a2.y);
    a2.z = fmaf(val, f5.x, a2.z); a2.w = fmaf(val, f5.y, a2.w);
    a3.x = fmaf(val, f6.x, a3.x); a3.y = fmaf(val, f6.y, a3.y);
    a3.z = fmaf(val, f7.x, a3.z); a3.w = fmaf(val, f7.y, a3.w);
  }
#define RED2(v) v += __shfl_xor(v, 16); v += __shfl_xor(v, 32);
  RED2(a0.x) RED2(a0.y) RED2(a0.z) RED2(a0.w)
  RED2(a1.x) RED2(a1.y) RED2(a1.z) RED2(a1.w)
  RED2(a2.x) RED2(a2.y) RED2(a2.z) RED2(a2.w)
  RED2(a3.x) RED2(a3.y) RED2(a3.z) RED2(a3.w)
#undef RED2
  if (qf == 0) {
    u16x8 o;
    o[0] = f2bu(fmaxf(a0.x, 0.f)); o[1] = f2bu(fmaxf(a0.y, 0.f));
    o[2] = f2bu(fmaxf(a0.z, 0.f)); o[3] = f2bu(fmaxf(a0.w, 0.f));
    o[4] = f2bu(fmaxf(a1.x, 0.f)); o[5] = f2bu(fmaxf(a1.y, 0.f));
    o[6] = f2bu(fmaxf(a1.z, 0.f)); o[7] = f2bu(fmaxf(a1.w, 0.f));
    *(u16x8*)(Y + (size_t)wave * N_HID + fl * 16) = o;
    o[0] = f2bu(fmaxf(a2.x, 0.f)); o[1] = f2bu(fmaxf(a2.y, 0.f));
    o[2] = f2bu(fmaxf(a2.z, 0.f)); o[3] = f2bu(fmaxf(a2.w, 0.f));
    o[4] = f2bu(fmaxf(a3.x, 0.f)); o[5] = f2bu(fmaxf(a3.y, 0.f));
    o[6] = f2bu(fmaxf(a3.z, 0.f)); o[7] = f2bu(fmaxf(a3.w, 0.f));
    *(u16x8*)(Y + (size_t)wave * N_HID + fl * 16 + 8) = o;
  }
}

// ---------------------------------------------------------------------------
// GEMM2: O[M,40](bf16) = Hpost[M,256](bf16) @ W2[256,40] + b2; 2 rows/thread.
// ---------------------------------------------------------------------------
__global__ __launch_bounds__(256) void gemm2_kernel(
    const unsigned short* __restrict__ H, const float* __restrict__ W2,
    const float* __restrict__ b2, unsigned short* __restrict__ O, int M) {
  __shared__ float Ws[N_HID * N_CLASS];
  __shared__ float sb2[N_CLASS];
  int tid = threadIdx.x;
  for (int i = tid; i < N_HID * N_CLASS; i += 256) Ws[i] = W2[i];
  if (tid < N_CLASS) sb2[tid] = b2[tid];
  __syncthreads();
  int r0 = (blockIdx.x * 256 + tid) * 2;
  if (r0 >= M) return;
  int r1 = r0 + 1;
  bool has1 = r1 < M;
  float acc0[N_CLASS], acc1[N_CLASS];
#pragma unroll
  for (int n = 0; n < N_CLASS; n++) { acc0[n] = sb2[n]; acc1[n] = sb2[n]; }
  const unsigned short* h0 = H + (size_t)r0 * N_HID;
  const unsigned short* h1 = H + (size_t)(has1 ? r1 : r0) * N_HID;
  for (int k0 = 0; k0 < N_HID; k0 += 8) {
    u16x8 va = *(const u16x8*)(h0 + k0);
    u16x8 vb = *(const u16x8*)(h1 + k0);
#pragma unroll
    for (int j = 0; j < 8; j++) {
      float a0 = b2f(va[j]), a1 = b2f(vb[j]);
      const float* wrow = &Ws[(k0 + j) * N_CLASS];
#pragma unroll
      for (int n = 0; n < N_CLASS; n++) {
        float wv = wrow[n];
        acc0[n] = fmaf(a0, wv, acc0[n]);
        acc1[n] = fmaf(a1, wv, acc1[n]);
      }
    }
  }
  unsigned short* o0 = O + (size_t)r0 * N_CLASS;
#pragma unroll
  for (int n = 0; n < N_CLASS; n += 4) {
    ushort4 p;
    p.x = f2bu(acc0[n]); p.y = f2bu(acc0[n + 1]);
    p.z = f2bu(acc0[n + 2]); p.w = f2bu(acc0[n + 3]);
    *(ushort4*)(o0 + n) = p;
  }
  if (has1) {
    unsigned short* o1 = O + (size_t)r1 * N_CLASS;
#pragma unroll
    for (int n = 0; n < N_CLASS; n += 4) {
      ushort4 p;
      p.x = f2bu(acc1[n]); p.y = f2bu(acc1[n + 1]);
      p.z = f2bu(acc1[n + 2]); p.w = f2bu(acc1[n + 3]);
      *(ushort4*)(o1 + n) = p;
    }
  }
}

// ---------------------------------------------------------------------------
// SPMM2 (F=40, bf16 X, packed cvp) + fused log_softmax: wave/row, unroll 4
// ---------------------------------------------------------------------------
__global__ __launch_bounds__(256) void spmm_csr_40_lsm(
    const int* __restrict__ row_ptr, const unsigned int* __restrict__ cvp,
    const unsigned short* __restrict__ X, float* __restrict__ Out, int M) {
  int wave = (blockIdx.x * 256 + threadIdx.x) >> 6;
  int lane = threadIdx.x & 63;
  if (wave >= M) return;
  int start = row_ptr[wave], end = row_ptr[wave + 1];
  bool act = lane < N_CLASS;
  int ln = act ? lane : 0;
  const unsigned short* Xc = X + ln;
  float acc = 0.f;
  int e = start;
  for (; e + 4 <= end; e += 4) {
    unsigned int p0 = cvp[e], p1 = cvp[e + 1], p2 = cvp[e + 2], p3 = cvp[e + 3];
    unsigned short x0 = Xc[(size_t)(p0 >> 15) * N_CLASS];
    unsigned short x1 = Xc[(size_t)(p1 >> 15) * N_CLASS];
    unsigned short x2 = Xc[(size_t)(p2 >> 15) * N_CLASS];
    unsigned short x3 = Xc[(size_t)(p3 >> 15) * N_CLASS];
    acc = fmaf(decode_val(p0), b2f(x0), acc);
    acc = fmaf(decode_val(p1), b2f(x1), acc);
    acc = fmaf(decode_val(p2), b2f(x2), acc);
    acc = fmaf(decode_val(p3), b2f(x3), acc);
  }
  for (; e < end; e++) {
    unsigned int p0 = cvp[e];
    acc = fmaf(decode_val(p0), b2f(Xc[(size_t)(p0 >> 15) * N_CLASS]), acc);
  }
  float mv = act ? acc : -INFINITY;
#pragma unroll
  for (int off = 32; off; off >>= 1) mv = fmaxf(mv, __shfl_xor(mv, off));
  float ex = act ? expf(acc - mv) : 0.f;
  float s = ex;
#pragma unroll
  for (int off = 32; off; off >>= 1) s += __shfl_xor(s, off);
  float lse = mv + logf(s);
  if (act) Out[(size_t)wave * N_CLASS + lane] = acc - lse;
}

// ---------------------------------------------------------------------------
extern "C" void kernel_launch(void* const* d_in, const int* in_sizes, int n_in,
                              void* d_out, int out_size, void* d_ws, size_t ws_size,
                              hipStream_t stream) {
  const float* feat = (const float*)d_in[0];
  const int* er     = (const int*)d_in[1];
  const int* ec     = (const int*)d_in[2];
  const float* ev   = (const float*)d_in[3];
  const float* W1   = (const float*)d_in[4];
  const float* b1   = (const float*)d_in[5];
  const float* W2   = (const float*)d_in[6];
  const float* b2   = (const float*)d_in[7];
  float* out = (float*)d_out;
  const int M = N_NODES;
  const int E = in_sizes[1];

  char* ws = (char*)d_ws;
  unsigned char* h      = (unsigned char*)(ws);                  // 25.6 MB fp8
  unsigned short* hpost = (unsigned short*)(ws + 25600000);      // 51.2 MB bf16
  unsigned short* o     = (unsigned short*)(ws + 76800000);      // 8 MB bf16
  int* row_ptr          = (int*)(ws + 84800000);                 // 400,004 B
  int* cursor           = (int*)(ws + 85200016);                 // 400,000 B
  int* bsum             = (int*)(ws + 85600016);                 // 512 B
  int* gcur             = (int*)(ws + 85600528);                 // 12,500 B
  unsigned int* cvp     = (unsigned int*)(ws + 85613328);        // 12.8 MB
  unsigned int* cvps    = (unsigned int*)(ws + 98413328);        // 12.8 MB
  unsigned short* W1Tsw = (unsigned short*)(ws + 111213328);     // 256 KB
  unsigned long long* grec = (unsigned long long*)(ws + 111475472);  // 32 MB

  const int NB1 = (M + 1023) / 1024;  // 98

  // zero cursor + bsum + gcur in one range (contiguous layout)
  (void)hipMemsetAsync(cursor, 0, 413040, stream);
  prep_kernel<<<1024, 256, 0, stream>>>(W1, W1Tsw, er, ec, ev, cursor, cvps, E);
  bin_kernel<<<2048, 256, 0, stream>>>(er, cvps, gcur, grec, E);
  scan1_kernel<<<NB1, 1024, 0, stream>>>(cursor, bsum, M);
  scan2_kernel<<<1, 64, 0, stream>>>(bsum, row_ptr, NB1, M);
  scan3_kernel<<<(M + 255) / 256, 256, 0, stream>>>(cursor, bsum, row_ptr, M);
  gather_kernel<<<(NG + 1) / 2, 256, 0, stream>>>(grec, gcur, cursor, cvp);
  gemm1_mfma<<<(M + 31) / 32, 256, 0, stream>>>(feat, W1Tsw, b1, h, M);
  spmm_fp8<<<(M + 3) / 4, 256, 0, stream>>>(row_ptr, cvp, h, hpost, M);
  gemm2_kernel<<<(M + 511) / 512, 256, 0, stream>>>(hpost, W2, b2, o, M);
  spmm_csr_40_lsm<<<(M + 3) / 4, 256, 0, stream>>>(row_ptr, cvp, o, out, M);
}

// Round 16
// 729.998 us; speedup vs baseline: 1.2729x; 1.2729x over previous
//
#include <hip/hip_runtime.h>
#include <hip/hip_bf16.h>
#include <math.h>

#define N_NODES 100000
#define N_FEAT 500
#define N_HID 256
#define N_CLASS 40

typedef float f32x4 __attribute__((ext_vector_type(4)));
typedef float f32x2 __attribute__((ext_vector_type(2)));
typedef int i32x4 __attribute__((ext_vector_type(4)));
typedef unsigned int u32x4 __attribute__((ext_vector_type(4)));
typedef short short8 __attribute__((ext_vector_type(8)));
typedef unsigned short u16x8 __attribute__((ext_vector_type(8)));

__device__ __forceinline__ float b2f(unsigned short u) {
  union { unsigned int i; float f; } c; c.i = ((unsigned int)u) << 16; return c.f;
}
__device__ __forceinline__ unsigned short f2bu(float x) {
  __hip_bfloat16 b = __float2bfloat16(x);
  union { __hip_bfloat16 b; unsigned short u; } c; c.b = b; return c.u;
}
__device__ __forceinline__ float decode_val(unsigned int p) {
  union { unsigned int i; float f; } c; c.i = (p & 0x7FFFu) << 17; return c.f;
}
__device__ __forceinline__ unsigned char f2fp8(float x) {
  return (unsigned char)(__builtin_amdgcn_cvt_pk_fp8_f32(x, x, 0, false) & 0xFF);
}
__device__ __forceinline__ void gload_lds16(const void* gptr, void* lptr) {
  __builtin_amdgcn_global_load_lds(
      (const __attribute__((address_space(1))) unsigned int*)gptr,
      (__attribute__((address_space(3))) unsigned int*)lptr, 16, 0, 0);
}

// ---------------------------------------------------------------------------
// prep (r12 exact): blocks 0..63 cast W1 -> W1Tsw bf16 swizzled; all blocks:
// histogram of er + pack cvps[i] = col<<15 | bf16(val)>>1, edge order.
// ---------------------------------------------------------------------------
__global__ __launch_bounds__(256) void prep_kernel(
    const float* __restrict__ W1, unsigned short* __restrict__ Bsw,
    const int* __restrict__ er, const int* __restrict__ ec,
    const float* __restrict__ ev, int* __restrict__ cnt,
    unsigned int* __restrict__ cvps, int E) {
  if (blockIdx.x < 64) {
    int t = blockIdx.x * 256 + threadIdx.x;
    int col = t >> 6, ch = t & 63;
    int g = ch >> 3, c = ch & 7;
    int c_src = c ^ (col & 7);
    int k = g * 64 + c_src * 8;
    u16x8 o;
#pragma unroll
    for (int j = 0; j < 8; j++) {
      int kk = k + j;
      o[j] = (kk < N_FEAT) ? f2bu(W1[(size_t)kk * N_HID + col]) : (unsigned short)0;
    }
    *(u16x8*)(Bsw + (size_t)col * 512 + g * 64 + c * 8) = o;
  }
  int nv = E >> 2;
  int t = blockIdx.x * 256 + threadIdx.x;
  int nthr = gridDim.x * 256;
  const i32x4* er4 = (const i32x4*)er;
  const i32x4* ec4 = (const i32x4*)ec;
  const f32x4* ev4 = (const f32x4*)ev;
  for (int i = t; i < nv; i += nthr) {
    i32x4 r = __builtin_nontemporal_load(&er4[i]);
    i32x4 c = __builtin_nontemporal_load(&ec4[i]);
    f32x4 v = __builtin_nontemporal_load(&ev4[i]);
    atomicAdd(&cnt[r.x], 1);
    atomicAdd(&cnt[r.y], 1);
    atomicAdd(&cnt[r.z], 1);
    atomicAdd(&cnt[r.w], 1);
    u32x4 pk;
    pk.x = ((unsigned int)c.x << 15) | ((unsigned int)f2bu(v.x) >> 1);
    pk.y = ((unsigned int)c.y << 15) | ((unsigned int)f2bu(v.y) >> 1);
    pk.z = ((unsigned int)c.z << 15) | ((unsigned int)f2bu(v.z) >> 1);
    pk.w = ((unsigned int)c.w << 15) | ((unsigned int)f2bu(v.w) >> 1);
    __builtin_nontemporal_store(pk, (u32x4*)(cvps + 4 * (size_t)i));
  }
  int tail = nv << 2;
  if (blockIdx.x == 0 && threadIdx.x < E - tail) {
    int i = tail + threadIdx.x;
    atomicAdd(&cnt[er[i]], 1);
    cvps[i] = ((unsigned int)ec[i] << 15) | ((unsigned int)f2bu(ev[i]) >> 1);
  }
}

// ---------------------------------------------------------------------------
// GEMM1 (bf16 MFMA, r12 exact): H[M,256] = A[M,500] @ W1 + b1, fp8 out.
// BM=32, BN=256, BK=64; 256 threads = 4 waves; 36 KB LDS.
// ---------------------------------------------------------------------------
__global__ __launch_bounds__(256) void gemm1_mfma(
    const float* __restrict__ A, const unsigned short* __restrict__ Bsw,
    const float* __restrict__ b1, unsigned char* __restrict__ H, int M) {
  __shared__ __align__(16) char smem[36864];
  char* sA = smem;            // [32 rows][128 B]
  char* sB = smem + 4096;     // [256 cols][128 B]
  int tid = threadIdx.x;
  int lane = tid & 63, w = tid >> 6;
  int wc = w;
  int bm = blockIdx.x * 32;

  f32x4 acc[2][4];
#pragma unroll
  for (int m = 0; m < 2; m++)
#pragma unroll
    for (int n = 0; n < 4; n++) acc[m][n] = (f32x4)0.f;

  for (int s = 0; s < 8; s++) {
    int k0 = s * 64;
#pragma unroll
    for (int i = 0; i < 2; i++) {
      int f4 = i * 256 + tid;
      int row = f4 >> 4, cidx = f4 & 15;
      int grow = bm + row;
      int k = k0 + cidx * 4;
      float4 v = make_float4(0.f, 0.f, 0.f, 0.f);
      if (grow < M && k < N_FEAT) v = *(const float4*)(A + (size_t)grow * N_FEAT + k);
      ushort4 u;
      u.x = f2bu(v.x); u.y = f2bu(v.y); u.z = f2bu(v.z); u.w = f2bu(v.w);
      int chunk = cidx >> 1, sub = cidx & 1;
      int byte = row * 128 + (((chunk ^ (row & 7))) << 4) + (sub << 3);
      *(ushort4*)(sA + byte) = u;
    }
#pragma unroll
    for (int j = 0; j < 8; j++) {
      int base = j * 4096 + w * 1024;
      int L = base + lane * 16;
      int col = L >> 7, c = (L >> 4) & 7;
      const char* g = (const char*)Bsw + (size_t)col * 1024 + s * 128 + c * 16;
      gload_lds16(g, sB + base);
    }
    __syncthreads();
#pragma unroll
    for (int kk = 0; kk < 2; kk++) {
      int cw = kk * 4 + (lane >> 4);
      short8 af[2], bg[4];
#pragma unroll
      for (int m = 0; m < 2; m++) {
        int ar = m * 16 + (lane & 15);
        af[m] = *(const short8*)(sA + ar * 128 + ((cw ^ (ar & 7)) << 4));
      }
#pragma unroll
      for (int n = 0; n < 4; n++) {
        int bc = wc * 64 + n * 16 + (lane & 15);
        bg[n] = *(const short8*)(sB + bc * 128 + ((cw ^ (bc & 7)) << 4));
      }
#pragma unroll
      for (int m = 0; m < 2; m++)
#pragma unroll
        for (int n = 0; n < 4; n++)
          acc[m][n] = __builtin_amdgcn_mfma_f32_16x16x32_bf16(af[m], bg[n], acc[m][n], 0, 0, 0);
    }
    __syncthreads();
  }

  float bias[4];
#pragma unroll
  for (int n = 0; n < 4; n++) bias[n] = b1[wc * 64 + n * 16 + (lane & 15)];
#pragma unroll
  for (int m = 0; m < 2; m++) {
#pragma unroll
    for (int r = 0; r < 4; r++) {
      int row = bm + m * 16 + ((lane >> 4) << 2) + r;
      if (row < M) {
#pragma unroll
        for (int n = 0; n < 4; n++) {
          int col = wc * 64 + n * 16 + (lane & 15);
          H[(size_t)row * N_HID + col] = f2fp8(acc[m][n][r] + bias[n]);
        }
      }
    }
  }
}

// ---------------------------------------------------------------------------
// scans (unchanged)
// ---------------------------------------------------------------------------
__global__ __launch_bounds__(1024) void scan1_kernel(
    int* __restrict__ cnt, int* __restrict__ bsum, int n) {
  __shared__ int wsum[16];
  int tid = threadIdx.x, lane = tid & 63, wid = tid >> 6;
  int i = blockIdx.x * 1024 + tid;
  int v = (i < n) ? cnt[i] : 0;
  int x = v;
#pragma unroll
  for (int off = 1; off < 64; off <<= 1) {
    int t = __shfl_up(x, off);
    if (lane >= off) x += t;
  }
  if (lane == 63) wsum[wid] = x;
  __syncthreads();
  if (tid < 16) {
    int ws = wsum[tid];
#pragma unroll
    for (int off = 1; off < 16; off <<= 1) {
      int t = __shfl_up(ws, off);
      if (tid >= off) ws += t;
    }
    wsum[tid] = ws;
  }
  __syncthreads();
  int excl = (wid ? wsum[wid - 1] : 0) + x - v;
  if (i < n) cnt[i] = excl;
  if (tid == 0) bsum[blockIdx.x] = wsum[15];
}

__global__ __launch_bounds__(64) void scan2_kernel(
    int* __restrict__ bsum, int* __restrict__ row_ptr, int nb, int n) {
  int lane = threadIdx.x;
  int carry = 0;
  for (int base = 0; base < nb; base += 64) {
    int i = base + lane;
    int v = (i < nb) ? bsum[i] : 0;
    int x = v;
#pragma unroll
    for (int off = 1; off < 64; off <<= 1) {
      int t = __shfl_up(x, off);
      if (lane >= off) x += t;
    }
    if (i < nb) bsum[i] = carry + x - v;
    carry += __shfl(x, 63);
  }
  if (lane == 0) row_ptr[n] = carry;
}

__global__ __launch_bounds__(256) void scan3_kernel(
    int* __restrict__ cnt, const int* __restrict__ bsum,
    int* __restrict__ row_ptr, int n) {
  int i = blockIdx.x * 256 + threadIdx.x;
  if (i >= n) return;
  int v = cnt[i] + bsum[i >> 10];
  cnt[i] = v;
  row_ptr[i] = v;
}

// ---------------------------------------------------------------------------
// XCD-sliced scatter, 2 slices, nontemporal cvp stores (reduce line churn).
// ---------------------------------------------------------------------------
__global__ __launch_bounds__(256) void scatter_kernel(
    const int* __restrict__ er, const unsigned int* __restrict__ cvps,
    int* __restrict__ cursor, unsigned int* __restrict__ cvp, int E) {
  int s = blockIdx.x & 1;
  int g = blockIdx.x >> 1;
  int ngrp = gridDim.x >> 1;
  int nv = E >> 2;
  const i32x4* er4 = (const i32x4*)er;
  const u32x4* cv4 = (const u32x4*)cvps;
  for (int i = g * 256 + threadIdx.x; i < nv; i += ngrp * 256) {
    i32x4 r = __builtin_nontemporal_load(&er4[i]);
    u32x4 p = __builtin_nontemporal_load(&cv4[i]);
    if (((r.x >> 9) & 1) == s) {
      int pos = atomicAdd(&cursor[r.x], 1);
      __builtin_nontemporal_store(p.x, &cvp[pos]);
    }
    if (((r.y >> 9) & 1) == s) {
      int pos = atomicAdd(&cursor[r.y], 1);
      __builtin_nontemporal_store(p.y, &cvp[pos]);
    }
    if (((r.z >> 9) & 1) == s) {
      int pos = atomicAdd(&cursor[r.z], 1);
      __builtin_nontemporal_store(p.z, &cvp[pos]);
    }
    if (((r.w >> 9) & 1) == s) {
      int pos = atomicAdd(&cursor[r.w], 1);
      __builtin_nontemporal_store(p.w, &cvp[pos]);
    }
  }
  int tail = nv << 2;
  if (blockIdx.x == 0 && threadIdx.x < E - tail) {
    int i = tail + threadIdx.x;
    cvp[atomicAdd(&cursor[er[i]], 1)] = cvps[i];
  }
}

// ---------------------------------------------------------------------------
// SPMM1 (CSR, F=256, fp8 X -> bf16 Y, fused ReLU): wave per row, 4 edges per
// step (16-lane groups), 16 feats x 16 B gather per lane, HW fp8 decode.
// cvp load pipelined one step ahead (breaks cvp->gather dependent chain).
// ---------------------------------------------------------------------------
__global__ __launch_bounds__(256) void spmm_fp8(
    const int* __restrict__ row_ptr, const unsigned int* __restrict__ cvp,
    const unsigned char* __restrict__ X, unsigned short* __restrict__ Y, int M) {
  int wave = (blockIdx.x * 256 + threadIdx.x) >> 6;
  int lane = threadIdx.x & 63;
  if (wave >= M) return;
  int start = row_ptr[wave], end = row_ptr[wave + 1];
  int qf = lane >> 4, fl = lane & 15;
  f32x4 a0 = (f32x4)0.f, a1 = (f32x4)0.f, a2 = (f32x4)0.f, a3 = (f32x4)0.f;
  const unsigned char* Xf = X + fl * 16;
  unsigned int pcur;
  {
    int ei = start + qf;
    pcur = (ei < end) ? cvp[ei] : 0u;
  }
#pragma unroll 2
  for (int e = start; e < end; e += 4) {
    int en = e + 4 + qf;
    unsigned int pnext = (en < end) ? cvp[en] : 0u;
    float val = decode_val(pcur);
    size_t col = (size_t)(pcur >> 15);
    u32x4 d = *(const u32x4*)(Xf + col * N_HID);
    f32x2 f0 = __builtin_amdgcn_cvt_pk_f32_fp8(d.x, false);
    f32x2 f1 = __builtin_amdgcn_cvt_pk_f32_fp8(d.x, true);
    f32x2 f2 = __builtin_amdgcn_cvt_pk_f32_fp8(d.y, false);
    f32x2 f3 = __builtin_amdgcn_cvt_pk_f32_fp8(d.y, true);
    f32x2 f4 = __builtin_amdgcn_cvt_pk_f32_fp8(d.z, false);
    f32x2 f5 = __builtin_amdgcn_cvt_pk_f32_fp8(d.z, true);
    f32x2 f6 = __builtin_amdgcn_cvt_pk_f32_fp8(d.w, false);
    f32x2 f7 = __builtin_amdgcn_cvt_pk_f32_fp8(d.w, true);
    a0.x = fmaf(val, f0.x, a0.x); a0.y = fmaf(val, f0.y, a0.y);
    a0.z = fmaf(val, f1.x, a0.z); a0.w = fmaf(val, f1.y, a0.w);
    a1.x = fmaf(val, f2.x, a1.x); a1.y = fmaf(val, f2.y, a1.y);
    a1.z = fmaf(val, f3.x, a1.z); a1.w = fmaf(val, f3.y, a1.w);
    a2.x = fmaf(val, f4.x, a2.x); a2.y = fmaf(val, f4.y, a2.y);
    a2.z = fmaf(val, f5.x, a2.z); a2.w = fmaf(val, f5.y, a2.w);
    a3.x = fmaf(val, f6.x, a3.x); a3.y = fmaf(val, f6.y, a3.y);
    a3.z = fmaf(val, f7.x, a3.z); a3.w = fmaf(val, f7.y, a3.w);
    pcur = pnext;
  }
#define RED2(v) v += __shfl_xor(v, 16); v += __shfl_xor(v, 32);
  RED2(a0.x) RED2(a0.y) RED2(a0.z) RED2(a0.w)
  RED2(a1.x) RED2(a1.y) RED2(a1.z) RED2(a1.w)
  RED2(a2.x) RED2(a2.y) RED2(a2.z) RED2(a2.w)
  RED2(a3.x) RED2(a3.y) RED2(a3.z) RED2(a3.w)
#undef RED2
  if (qf == 0) {
    u16x8 o;
    o[0] = f2bu(fmaxf(a0.x, 0.f)); o[1] = f2bu(fmaxf(a0.y, 0.f));
    o[2] = f2bu(fmaxf(a0.z, 0.f)); o[3] = f2bu(fmaxf(a0.w, 0.f));
    o[4] = f2bu(fmaxf(a1.x, 0.f)); o[5] = f2bu(fmaxf(a1.y, 0.f));
    o[6] = f2bu(fmaxf(a1.z, 0.f)); o[7] = f2bu(fmaxf(a1.w, 0.f));
    *(u16x8*)(Y + (size_t)wave * N_HID + fl * 16) = o;
    o[0] = f2bu(fmaxf(a2.x, 0.f)); o[1] = f2bu(fmaxf(a2.y, 0.f));
    o[2] = f2bu(fmaxf(a2.z, 0.f)); o[3] = f2bu(fmaxf(a2.w, 0.f));
    o[4] = f2bu(fmaxf(a3.x, 0.f)); o[5] = f2bu(fmaxf(a3.y, 0.f));
    o[6] = f2bu(fmaxf(a3.z, 0.f)); o[7] = f2bu(fmaxf(a3.w, 0.f));
    *(u16x8*)(Y + (size_t)wave * N_HID + fl * 16 + 8) = o;
  }
}

// ---------------------------------------------------------------------------
// GEMM2: O[M,40](bf16) = Hpost[M,256](bf16) @ W2[256,40] + b2; 2 rows/thread.
// ---------------------------------------------------------------------------
__global__ __launch_bounds__(256) void gemm2_kernel(
    const unsigned short* __restrict__ H, const float* __restrict__ W2,
    const float* __restrict__ b2, unsigned short* __restrict__ O, int M) {
  __shared__ float Ws[N_HID * N_CLASS];
  __shared__ float sb2[N_CLASS];
  int tid = threadIdx.x;
  for (int i = tid; i < N_HID * N_CLASS; i += 256) Ws[i] = W2[i];
  if (tid < N_CLASS) sb2[tid] = b2[tid];
  __syncthreads();
  int r0 = (blockIdx.x * 256 + tid) * 2;
  if (r0 >= M) return;
  int r1 = r0 + 1;
  bool has1 = r1 < M;
  float acc0[N_CLASS], acc1[N_CLASS];
#pragma unroll
  for (int n = 0; n < N_CLASS; n++) { acc0[n] = sb2[n]; acc1[n] = sb2[n]; }
  const unsigned short* h0 = H + (size_t)r0 * N_HID;
  const unsigned short* h1 = H + (size_t)(has1 ? r1 : r0) * N_HID;
  for (int k0 = 0; k0 < N_HID; k0 += 8) {
    u16x8 va = *(const u16x8*)(h0 + k0);
    u16x8 vb = *(const u16x8*)(h1 + k0);
#pragma unroll
    for (int j = 0; j < 8; j++) {
      float a0 = b2f(va[j]), a1 = b2f(vb[j]);
      const float* wrow = &Ws[(k0 + j) * N_CLASS];
#pragma unroll
      for (int n = 0; n < N_CLASS; n++) {
        float wv = wrow[n];
        acc0[n] = fmaf(a0, wv, acc0[n]);
        acc1[n] = fmaf(a1, wv, acc1[n]);
      }
    }
  }
  unsigned short* o0 = O + (size_t)r0 * N_CLASS;
#pragma unroll
  for (int n = 0; n < N_CLASS; n += 4) {
    ushort4 p;
    p.x = f2bu(acc0[n]); p.y = f2bu(acc0[n + 1]);
    p.z = f2bu(acc0[n + 2]); p.w = f2bu(acc0[n + 3]);
    *(ushort4*)(o0 + n) = p;
  }
  if (has1) {
    unsigned short* o1 = O + (size_t)r1 * N_CLASS;
#pragma unroll
    for (int n = 0; n < N_CLASS; n += 4) {
      ushort4 p;
      p.x = f2bu(acc1[n]); p.y = f2bu(acc1[n + 1]);
      p.z = f2bu(acc1[n + 2]); p.w = f2bu(acc1[n + 3]);
      *(ushort4*)(o1 + n) = p;
    }
  }
}

// ---------------------------------------------------------------------------
// SPMM2 (F=40, bf16 X, packed cvp) + fused log_softmax: wave/row, unroll 4
// ---------------------------------------------------------------------------
__global__ __launch_bounds__(256) void spmm_csr_40_lsm(
    const int* __restrict__ row_ptr, const unsigned int* __restrict__ cvp,
    const unsigned short* __restrict__ X, float* __restrict__ Out, int M) {
  int wave = (blockIdx.x * 256 + threadIdx.x) >> 6;
  int lane = threadIdx.x & 63;
  if (wave >= M) return;
  int start = row_ptr[wave], end = row_ptr[wave + 1];
  bool act = lane < N_CLASS;
  int ln = act ? lane : 0;
  const unsigned short* Xc = X + ln;
  float acc = 0.f;
  int e = start;
  for (; e + 4 <= end; e += 4) {
    unsigned int p0 = cvp[e], p1 = cvp[e + 1], p2 = cvp[e + 2], p3 = cvp[e + 3];
    unsigned short x0 = Xc[(size_t)(p0 >> 15) * N_CLASS];
    unsigned short x1 = Xc[(size_t)(p1 >> 15) * N_CLASS];
    unsigned short x2 = Xc[(size_t)(p2 >> 15) * N_CLASS];
    unsigned short x3 = Xc[(size_t)(p3 >> 15) * N_CLASS];
    acc = fmaf(decode_val(p0), b2f(x0), acc);
    acc = fmaf(decode_val(p1), b2f(x1), acc);
    acc = fmaf(decode_val(p2), b2f(x2), acc);
    acc = fmaf(decode_val(p3), b2f(x3), acc);
  }
  for (; e < end; e++) {
    unsigned int p0 = cvp[e];
    acc = fmaf(decode_val(p0), b2f(Xc[(size_t)(p0 >> 15) * N_CLASS]), acc);
  }
  float mv = act ? acc : -INFINITY;
#pragma unroll
  for (int off = 32; off; off >>= 1) mv = fmaxf(mv, __shfl_xor(mv, off));
  float ex = act ? expf(acc - mv) : 0.f;
  float s = ex;
#pragma unroll
  for (int off = 32; off; off >>= 1) s += __shfl_xor(s, off);
  float lse = mv + logf(s);
  if (act) Out[(size_t)wave * N_CLASS + lane] = acc - lse;
}

// ---------------------------------------------------------------------------
extern "C" void kernel_launch(void* const* d_in, const int* in_sizes, int n_in,
                              void* d_out, int out_size, void* d_ws, size_t ws_size,
                              hipStream_t stream) {
  const float* feat = (const float*)d_in[0];
  const int* er     = (const int*)d_in[1];
  const int* ec     = (const int*)d_in[2];
  const float* ev   = (const float*)d_in[3];
  const float* W1   = (const float*)d_in[4];
  const float* b1   = (const float*)d_in[5];
  const float* W2   = (const float*)d_in[6];
  const float* b2   = (const float*)d_in[7];
  float* out = (float*)d_out;
  const int M = N_NODES;
  const int E = in_sizes[1];

  char* ws = (char*)d_ws;
  unsigned char* h      = (unsigned char*)(ws);                  // 25.6 MB fp8
  unsigned short* hpost = (unsigned short*)(ws + 25600000);      // 51.2 MB bf16
  unsigned short* o     = (unsigned short*)(ws + 76800000);      // 8 MB bf16
  int* row_ptr          = (int*)(ws + 84800000);                 // 400,004 B
  int* cursor           = (int*)(ws + 85200016);                 // 400,000 B
  int* bsum             = (int*)(ws + 85600016);                 // 512 B
  unsigned int* cvp     = (unsigned int*)(ws + 85600528);        // 12.8 MB
  unsigned int* cvps    = (unsigned int*)(ws + 98400528);        // 12.8 MB
  unsigned short* W1Tsw = (unsigned short*)(ws + 111200528);     // 256 KB

  const int NB1 = (M + 1023) / 1024;  // 98

  (void)hipMemsetAsync(cursor, 0, (size_t)M * sizeof(int), stream);
  prep_kernel<<<1024, 256, 0, stream>>>(W1, W1Tsw, er, ec, ev, cursor, cvps, E);
  scan1_kernel<<<NB1, 1024, 0, stream>>>(cursor, bsum, M);
  scan2_kernel<<<1, 64, 0, stream>>>(bsum, row_ptr, NB1, M);
  scan3_kernel<<<(M + 255) / 256, 256, 0, stream>>>(cursor, bsum, row_ptr, M);
  scatter_kernel<<<2048, 256, 0, stream>>>(er, cvps, cursor, cvp, E);
  gemm1_mfma<<<(M + 31) / 32, 256, 0, stream>>>(feat, W1Tsw, b1, h, M);
  spmm_fp8<<<(M + 3) / 4, 256, 0, stream>>>(row_ptr, cvp, h, hpost, M);
  gemm2_kernel<<<(M + 511) / 512, 256, 0, stream>>>(hpost, W2, b2, o, M);
  spmm_csr_40_lsm<<<(M + 3) / 4, 256, 0, stream>>>(row_ptr, cvp, o, out, M);
}

// Round 17
// 650.263 us; speedup vs baseline: 1.4290x; 1.1226x over previous
//
#include <hip/hip_runtime.h>
#include <hip/hip_bf16.h>
#include <math.h>

#define N_NODES 100000
#define N_FEAT 500
#define N_HID 256
#define N_CLASS 40

typedef float f32x4 __attribute__((ext_vector_type(4)));
typedef float f32x2 __attribute__((ext_vector_type(2)));
typedef int i32x4 __attribute__((ext_vector_type(4)));
typedef unsigned int u32x4 __attribute__((ext_vector_type(4)));
typedef short short8 __attribute__((ext_vector_type(8)));
typedef unsigned short u16x8 __attribute__((ext_vector_type(8)));

__device__ __forceinline__ float b2f(unsigned short u) {
  union { unsigned int i; float f; } c; c.i = ((unsigned int)u) << 16; return c.f;
}
__device__ __forceinline__ unsigned short f2bu(float x) {
  __hip_bfloat16 b = __float2bfloat16(x);
  union { __hip_bfloat16 b; unsigned short u; } c; c.b = b; return c.u;
}
__device__ __forceinline__ float decode_val(unsigned int p) {
  union { unsigned int i; float f; } c; c.i = (p & 0x7FFFu) << 17; return c.f;
}
__device__ __forceinline__ unsigned char f2fp8(float x) {
  return (unsigned char)(__builtin_amdgcn_cvt_pk_fp8_f32(x, x, 0, false) & 0xFF);
}
__device__ __forceinline__ void gload_lds16(const void* gptr, void* lptr) {
  __builtin_amdgcn_global_load_lds(
      (const __attribute__((address_space(1))) unsigned int*)gptr,
      (__attribute__((address_space(3))) unsigned int*)lptr, 16, 0, 0);
}

// ---------------------------------------------------------------------------
// prep (r12 exact): blocks 0..63 cast W1 -> W1Tsw bf16 swizzled; all blocks:
// histogram of er + pack cvps[i] = col<<15 | bf16(val)>>1, edge order.
// ---------------------------------------------------------------------------
__global__ __launch_bounds__(256) void prep_kernel(
    const float* __restrict__ W1, unsigned short* __restrict__ Bsw,
    const int* __restrict__ er, const int* __restrict__ ec,
    const float* __restrict__ ev, int* __restrict__ cnt,
    unsigned int* __restrict__ cvps, int E) {
  if (blockIdx.x < 64) {
    int t = blockIdx.x * 256 + threadIdx.x;
    int col = t >> 6, ch = t & 63;
    int g = ch >> 3, c = ch & 7;
    int c_src = c ^ (col & 7);
    int k = g * 64 + c_src * 8;
    u16x8 o;
#pragma unroll
    for (int j = 0; j < 8; j++) {
      int kk = k + j;
      o[j] = (kk < N_FEAT) ? f2bu(W1[(size_t)kk * N_HID + col]) : (unsigned short)0;
    }
    *(u16x8*)(Bsw + (size_t)col * 512 + g * 64 + c * 8) = o;
  }
  int nv = E >> 2;
  int t = blockIdx.x * 256 + threadIdx.x;
  int nthr = gridDim.x * 256;
  const i32x4* er4 = (const i32x4*)er;
  const i32x4* ec4 = (const i32x4*)ec;
  const f32x4* ev4 = (const f32x4*)ev;
  for (int i = t; i < nv; i += nthr) {
    i32x4 r = __builtin_nontemporal_load(&er4[i]);
    i32x4 c = __builtin_nontemporal_load(&ec4[i]);
    f32x4 v = __builtin_nontemporal_load(&ev4[i]);
    atomicAdd(&cnt[r.x], 1);
    atomicAdd(&cnt[r.y], 1);
    atomicAdd(&cnt[r.z], 1);
    atomicAdd(&cnt[r.w], 1);
    u32x4 pk;
    pk.x = ((unsigned int)c.x << 15) | ((unsigned int)f2bu(v.x) >> 1);
    pk.y = ((unsigned int)c.y << 15) | ((unsigned int)f2bu(v.y) >> 1);
    pk.z = ((unsigned int)c.z << 15) | ((unsigned int)f2bu(v.z) >> 1);
    pk.w = ((unsigned int)c.w << 15) | ((unsigned int)f2bu(v.w) >> 1);
    __builtin_nontemporal_store(pk, (u32x4*)(cvps + 4 * (size_t)i));
  }
  int tail = nv << 2;
  if (blockIdx.x == 0 && threadIdx.x < E - tail) {
    int i = tail + threadIdx.x;
    atomicAdd(&cnt[er[i]], 1);
    cvps[i] = ((unsigned int)ec[i] << 15) | ((unsigned int)f2bu(ev[i]) >> 1);
  }
}

// ---------------------------------------------------------------------------
// GEMM1 (bf16 MFMA, r12 exact): H[M,256] = A[M,500] @ W1 + b1, fp8 out.
// BM=32, BN=256, BK=64; 256 threads = 4 waves; 36 KB LDS.
// ---------------------------------------------------------------------------
__global__ __launch_bounds__(256) void gemm1_mfma(
    const float* __restrict__ A, const unsigned short* __restrict__ Bsw,
    const float* __restrict__ b1, unsigned char* __restrict__ H, int M) {
  __shared__ __align__(16) char smem[36864];
  char* sA = smem;            // [32 rows][128 B]
  char* sB = smem + 4096;     // [256 cols][128 B]
  int tid = threadIdx.x;
  int lane = tid & 63, w = tid >> 6;
  int wc = w;
  int bm = blockIdx.x * 32;

  f32x4 acc[2][4];
#pragma unroll
  for (int m = 0; m < 2; m++)
#pragma unroll
    for (int n = 0; n < 4; n++) acc[m][n] = (f32x4)0.f;

  for (int s = 0; s < 8; s++) {
    int k0 = s * 64;
#pragma unroll
    for (int i = 0; i < 2; i++) {
      int f4 = i * 256 + tid;
      int row = f4 >> 4, cidx = f4 & 15;
      int grow = bm + row;
      int k = k0 + cidx * 4;
      float4 v = make_float4(0.f, 0.f, 0.f, 0.f);
      if (grow < M && k < N_FEAT) v = *(const float4*)(A + (size_t)grow * N_FEAT + k);
      ushort4 u;
      u.x = f2bu(v.x); u.y = f2bu(v.y); u.z = f2bu(v.z); u.w = f2bu(v.w);
      int chunk = cidx >> 1, sub = cidx & 1;
      int byte = row * 128 + (((chunk ^ (row & 7))) << 4) + (sub << 3);
      *(ushort4*)(sA + byte) = u;
    }
#pragma unroll
    for (int j = 0; j < 8; j++) {
      int base = j * 4096 + w * 1024;
      int L = base + lane * 16;
      int col = L >> 7, c = (L >> 4) & 7;
      const char* g = (const char*)Bsw + (size_t)col * 1024 + s * 128 + c * 16;
      gload_lds16(g, sB + base);
    }
    __syncthreads();
#pragma unroll
    for (int kk = 0; kk < 2; kk++) {
      int cw = kk * 4 + (lane >> 4);
      short8 af[2], bg[4];
#pragma unroll
      for (int m = 0; m < 2; m++) {
        int ar = m * 16 + (lane & 15);
        af[m] = *(const short8*)(sA + ar * 128 + ((cw ^ (ar & 7)) << 4));
      }
#pragma unroll
      for (int n = 0; n < 4; n++) {
        int bc = wc * 64 + n * 16 + (lane & 15);
        bg[n] = *(const short8*)(sB + bc * 128 + ((cw ^ (bc & 7)) << 4));
      }
#pragma unroll
      for (int m = 0; m < 2; m++)
#pragma unroll
        for (int n = 0; n < 4; n++)
          acc[m][n] = __builtin_amdgcn_mfma_f32_16x16x32_bf16(af[m], bg[n], acc[m][n], 0, 0, 0);
    }
    __syncthreads();
  }

  float bias[4];
#pragma unroll
  for (int n = 0; n < 4; n++) bias[n] = b1[wc * 64 + n * 16 + (lane & 15)];
#pragma unroll
  for (int m = 0; m < 2; m++) {
#pragma unroll
    for (int r = 0; r < 4; r++) {
      int row = bm + m * 16 + ((lane >> 4) << 2) + r;
      if (row < M) {
#pragma unroll
        for (int n = 0; n < 4; n++) {
          int col = wc * 64 + n * 16 + (lane & 15);
          H[(size_t)row * N_HID + col] = f2fp8(acc[m][n][r] + bias[n]);
        }
      }
    }
  }
}

// ---------------------------------------------------------------------------
// scans (unchanged)
// ---------------------------------------------------------------------------
__global__ __launch_bounds__(1024) void scan1_kernel(
    int* __restrict__ cnt, int* __restrict__ bsum, int n) {
  __shared__ int wsum[16];
  int tid = threadIdx.x, lane = tid & 63, wid = tid >> 6;
  int i = blockIdx.x * 1024 + tid;
  int v = (i < n) ? cnt[i] : 0;
  int x = v;
#pragma unroll
  for (int off = 1; off < 64; off <<= 1) {
    int t = __shfl_up(x, off);
    if (lane >= off) x += t;
  }
  if (lane == 63) wsum[wid] = x;
  __syncthreads();
  if (tid < 16) {
    int ws = wsum[tid];
#pragma unroll
    for (int off = 1; off < 16; off <<= 1) {
      int t = __shfl_up(ws, off);
      if (tid >= off) ws += t;
    }
    wsum[tid] = ws;
  }
  __syncthreads();
  int excl = (wid ? wsum[wid - 1] : 0) + x - v;
  if (i < n) cnt[i] = excl;
  if (tid == 0) bsum[blockIdx.x] = wsum[15];
}

__global__ __launch_bounds__(64) void scan2_kernel(
    int* __restrict__ bsum, int* __restrict__ row_ptr, int nb, int n) {
  int lane = threadIdx.x;
  int carry = 0;
  for (int base = 0; base < nb; base += 64) {
    int i = base + lane;
    int v = (i < nb) ? bsum[i] : 0;
    int x = v;
#pragma unroll
    for (int off = 1; off < 64; off <<= 1) {
      int t = __shfl_up(x, off);
      if (lane >= off) x += t;
    }
    if (i < nb) bsum[i] = carry + x - v;
    carry += __shfl(x, 63);
  }
  if (lane == 0) row_ptr[n] = carry;
}

__global__ __launch_bounds__(256) void scan3_kernel(
    int* __restrict__ cnt, const int* __restrict__ bsum,
    int* __restrict__ row_ptr, int n) {
  int i = blockIdx.x * 256 + threadIdx.x;
  if (i >= n) return;
  int v = cnt[i] + bsum[i >> 10];
  cnt[i] = v;
  row_ptr[i] = v;
}

// ---------------------------------------------------------------------------
// XCD-sliced scatter (r12 exact): 4 slices, plain stores.
// ---------------------------------------------------------------------------
__global__ __launch_bounds__(256) void scatter_kernel(
    const int* __restrict__ er, const unsigned int* __restrict__ cvps,
    int* __restrict__ cursor, unsigned int* __restrict__ cvp, int E) {
  int s = blockIdx.x & 3;
  int g = blockIdx.x >> 2;
  int ngrp = gridDim.x >> 2;
  int nv = E >> 2;
  const i32x4* er4 = (const i32x4*)er;
  const u32x4* cv4 = (const u32x4*)cvps;
  for (int i = g * 256 + threadIdx.x; i < nv; i += ngrp * 256) {
    i32x4 r = __builtin_nontemporal_load(&er4[i]);
    u32x4 p = __builtin_nontemporal_load(&cv4[i]);
    if (((r.x >> 9) & 3) == s) cvp[atomicAdd(&cursor[r.x], 1)] = p.x;
    if (((r.y >> 9) & 3) == s) cvp[atomicAdd(&cursor[r.y], 1)] = p.y;
    if (((r.z >> 9) & 3) == s) cvp[atomicAdd(&cursor[r.z], 1)] = p.z;
    if (((r.w >> 9) & 3) == s) cvp[atomicAdd(&cursor[r.w], 1)] = p.w;
  }
  int tail = nv << 2;
  if (blockIdx.x == 0 && threadIdx.x < E - tail) {
    int i = tail + threadIdx.x;
    cvp[atomicAdd(&cursor[er[i]], 1)] = cvps[i];
  }
}

// ---------------------------------------------------------------------------
// SPMM1 (CSR, F=256, fp8 X -> bf16 Y, fused ReLU): wave per row, 4 edges per
// step (16-lane groups), 16 feats x 16 B gather per lane, HW fp8 decode;
// cvp load pipelined one step ahead (r16 validated).
// ---------------------------------------------------------------------------
__global__ __launch_bounds__(256) void spmm_fp8(
    const int* __restrict__ row_ptr, const unsigned int* __restrict__ cvp,
    const unsigned char* __restrict__ X, unsigned short* __restrict__ Y, int M) {
  int wave = (blockIdx.x * 256 + threadIdx.x) >> 6;
  int lane = threadIdx.x & 63;
  if (wave >= M) return;
  int start = row_ptr[wave], end = row_ptr[wave + 1];
  int qf = lane >> 4, fl = lane & 15;
  f32x4 a0 = (f32x4)0.f, a1 = (f32x4)0.f, a2 = (f32x4)0.f, a3 = (f32x4)0.f;
  const unsigned char* Xf = X + fl * 16;
  unsigned int pcur;
  {
    int ei = start + qf;
    pcur = (ei < end) ? cvp[ei] : 0u;
  }
#pragma unroll 2
  for (int e = start; e < end; e += 4) {
    int en = e + 4 + qf;
    unsigned int pnext = (en < end) ? cvp[en] : 0u;
    float val = decode_val(pcur);
    size_t col = (size_t)(pcur >> 15);
    u32x4 d = *(const u32x4*)(Xf + col * N_HID);
    f32x2 f0 = __builtin_amdgcn_cvt_pk_f32_fp8(d.x, false);
    f32x2 f1 = __builtin_amdgcn_cvt_pk_f32_fp8(d.x, true);
    f32x2 f2 = __builtin_amdgcn_cvt_pk_f32_fp8(d.y, false);
    f32x2 f3 = __builtin_amdgcn_cvt_pk_f32_fp8(d.y, true);
    f32x2 f4 = __builtin_amdgcn_cvt_pk_f32_fp8(d.z, false);
    f32x2 f5 = __builtin_amdgcn_cvt_pk_f32_fp8(d.z, true);
    f32x2 f6 = __builtin_amdgcn_cvt_pk_f32_fp8(d.w, false);
    f32x2 f7 = __builtin_amdgcn_cvt_pk_f32_fp8(d.w, true);
    a0.x = fmaf(val, f0.x, a0.x); a0.y = fmaf(val, f0.y, a0.y);
    a0.z = fmaf(val, f1.x, a0.z); a0.w = fmaf(val, f1.y, a0.w);
    a1.x = fmaf(val, f2.x, a1.x); a1.y = fmaf(val, f2.y, a1.y);
    a1.z = fmaf(val, f3.x, a1.z); a1.w = fmaf(val, f3.y, a1.w);
    a2.x = fmaf(val, f4.x, a2.x); a2.y = fmaf(val, f4.y, a2.y);
    a2.z = fmaf(val, f5.x, a2.z); a2.w = fmaf(val, f5.y, a2.w);
    a3.x = fmaf(val, f6.x, a3.x); a3.y = fmaf(val, f6.y, a3.y);
    a3.z = fmaf(val, f7.x, a3.z); a3.w = fmaf(val, f7.y, a3.w);
    pcur = pnext;
  }
#define RED2(v) v += __shfl_xor(v, 16); v += __shfl_xor(v, 32);
  RED2(a0.x) RED2(a0.y) RED2(a0.z) RED2(a0.w)
  RED2(a1.x) RED2(a1.y) RED2(a1.z) RED2(a1.w)
  RED2(a2.x) RED2(a2.y) RED2(a2.z) RED2(a2.w)
  RED2(a3.x) RED2(a3.y) RED2(a3.z) RED2(a3.w)
#undef RED2
  if (qf == 0) {
    u16x8 o;
    o[0] = f2bu(fmaxf(a0.x, 0.f)); o[1] = f2bu(fmaxf(a0.y, 0.f));
    o[2] = f2bu(fmaxf(a0.z, 0.f)); o[3] = f2bu(fmaxf(a0.w, 0.f));
    o[4] = f2bu(fmaxf(a1.x, 0.f)); o[5] = f2bu(fmaxf(a1.y, 0.f));
    o[6] = f2bu(fmaxf(a1.z, 0.f)); o[7] = f2bu(fmaxf(a1.w, 0.f));
    *(u16x8*)(Y + (size_t)wave * N_HID + fl * 16) = o;
    o[0] = f2bu(fmaxf(a2.x, 0.f)); o[1] = f2bu(fmaxf(a2.y, 0.f));
    o[2] = f2bu(fmaxf(a2.z, 0.f)); o[3] = f2bu(fmaxf(a2.w, 0.f));
    o[4] = f2bu(fmaxf(a3.x, 0.f)); o[5] = f2bu(fmaxf(a3.y, 0.f));
    o[6] = f2bu(fmaxf(a3.z, 0.f)); o[7] = f2bu(fmaxf(a3.w, 0.f));
    *(u16x8*)(Y + (size_t)wave * N_HID + fl * 16 + 8) = o;
  }
}

// ---------------------------------------------------------------------------
// GEMM2: O[M,40](bf16) = Hpost[M,256](bf16) @ W2[256,40] + b2; 2 rows/thread.
// ---------------------------------------------------------------------------
__global__ __launch_bounds__(256) void gemm2_kernel(
    const unsigned short* __restrict__ H, const float* __restrict__ W2,
    const float* __restrict__ b2, unsigned short* __restrict__ O, int M) {
  __shared__ float Ws[N_HID * N_CLASS];
  __shared__ float sb2[N_CLASS];
  int tid = threadIdx.x;
  for (int i = tid; i < N_HID * N_CLASS; i += 256) Ws[i] = W2[i];
  if (tid < N_CLASS) sb2[tid] = b2[tid];
  __syncthreads();
  int r0 = (blockIdx.x * 256 + tid) * 2;
  if (r0 >= M) return;
  int r1 = r0 + 1;
  bool has1 = r1 < M;
  float acc0[N_CLASS], acc1[N_CLASS];
#pragma unroll
  for (int n = 0; n < N_CLASS; n++) { acc0[n] = sb2[n]; acc1[n] = sb2[n]; }
  const unsigned short* h0 = H + (size_t)r0 * N_HID;
  const unsigned short* h1 = H + (size_t)(has1 ? r1 : r0) * N_HID;
  for (int k0 = 0; k0 < N_HID; k0 += 8) {
    u16x8 va = *(const u16x8*)(h0 + k0);
    u16x8 vb = *(const u16x8*)(h1 + k0);
#pragma unroll
    for (int j = 0; j < 8; j++) {
      float a0 = b2f(va[j]), a1 = b2f(vb[j]);
      const float* wrow = &Ws[(k0 + j) * N_CLASS];
#pragma unroll
      for (int n = 0; n < N_CLASS; n++) {
        float wv = wrow[n];
        acc0[n] = fmaf(a0, wv, acc0[n]);
        acc1[n] = fmaf(a1, wv, acc1[n]);
      }
    }
  }
  unsigned short* o0 = O + (size_t)r0 * N_CLASS;
#pragma unroll
  for (int n = 0; n < N_CLASS; n += 4) {
    ushort4 p;
    p.x = f2bu(acc0[n]); p.y = f2bu(acc0[n + 1]);
    p.z = f2bu(acc0[n + 2]); p.w = f2bu(acc0[n + 3]);
    *(ushort4*)(o0 + n) = p;
  }
  if (has1) {
    unsigned short* o1 = O + (size_t)r1 * N_CLASS;
#pragma unroll
    for (int n = 0; n < N_CLASS; n += 4) {
      ushort4 p;
      p.x = f2bu(acc1[n]); p.y = f2bu(acc1[n + 1]);
      p.z = f2bu(acc1[n + 2]); p.w = f2bu(acc1[n + 3]);
      *(ushort4*)(o1 + n) = p;
    }
  }
}

// ---------------------------------------------------------------------------
// SPMM2 (F=40, bf16 X, packed cvp) + fused log_softmax: wave/row, unroll 4
// ---------------------------------------------------------------------------
__global__ __launch_bounds__(256) void spmm_csr_40_lsm(
    const int* __restrict__ row_ptr, const unsigned int* __restrict__ cvp,
    const unsigned short* __restrict__ X, float* __restrict__ Out, int M) {
  int wave = (blockIdx.x * 256 + threadIdx.x) >> 6;
  int lane = threadIdx.x & 63;
  if (wave >= M) return;
  int start = row_ptr[wave], end = row_ptr[wave + 1];
  bool act = lane < N_CLASS;
  int ln = act ? lane : 0;
  const unsigned short* Xc = X + ln;
  float acc = 0.f;
  int e = start;
  for (; e + 4 <= end; e += 4) {
    unsigned int p0 = cvp[e], p1 = cvp[e + 1], p2 = cvp[e + 2], p3 = cvp[e + 3];
    unsigned short x0 = Xc[(size_t)(p0 >> 15) * N_CLASS];
    unsigned short x1 = Xc[(size_t)(p1 >> 15) * N_CLASS];
    unsigned short x2 = Xc[(size_t)(p2 >> 15) * N_CLASS];
    unsigned short x3 = Xc[(size_t)(p3 >> 15) * N_CLASS];
    acc = fmaf(decode_val(p0), b2f(x0), acc);
    acc = fmaf(decode_val(p1), b2f(x1), acc);
    acc = fmaf(decode_val(p2), b2f(x2), acc);
    acc = fmaf(decode_val(p3), b2f(x3), acc);
  }
  for (; e < end; e++) {
    unsigned int p0 = cvp[e];
    acc = fmaf(decode_val(p0), b2f(Xc[(size_t)(p0 >> 15) * N_CLASS]), acc);
  }
  float mv = act ? acc : -INFINITY;
#pragma unroll
  for (int off = 32; off; off >>= 1) mv = fmaxf(mv, __shfl_xor(mv, off));
  float ex = act ? expf(acc - mv) : 0.f;
  float s = ex;
#pragma unroll
  for (int off = 32; off; off >>= 1) s += __shfl_xor(s, off);
  float lse = mv + logf(s);
  if (act) Out[(size_t)wave * N_CLASS + lane] = acc - lse;
}

// ---------------------------------------------------------------------------
extern "C" void kernel_launch(void* const* d_in, const int* in_sizes, int n_in,
                              void* d_out, int out_size, void* d_ws, size_t ws_size,
                              hipStream_t stream) {
  const float* feat = (const float*)d_in[0];
  const int* er     = (const int*)d_in[1];
  const int* ec     = (const int*)d_in[2];
  const float* ev   = (const float*)d_in[3];
  const float* W1   = (const float*)d_in[4];
  const float* b1   = (const float*)d_in[5];
  const float* W2   = (const float*)d_in[6];
  const float* b2   = (const float*)d_in[7];
  float* out = (float*)d_out;
  const int M = N_NODES;
  const int E = in_sizes[1];

  char* ws = (char*)d_ws;
  unsigned char* h      = (unsigned char*)(ws);                  // 25.6 MB fp8
  unsigned short* hpost = (unsigned short*)(ws + 25600000);      // 51.2 MB bf16
  unsigned short* o     = (unsigned short*)(ws + 76800000);      // 8 MB bf16
  int* row_ptr          = (int*)(ws + 84800000);                 // 400,004 B
  int* cursor           = (int*)(ws + 85200016);                 // 400,000 B
  int* bsum             = (int*)(ws + 85600016);                 // 512 B
  unsigned int* cvp     = (unsigned int*)(ws + 85600528);        // 12.8 MB
  unsigned int* cvps    = (unsigned int*)(ws + 98400528);        // 12.8 MB
  unsigned short* W1Tsw = (unsigned short*)(ws + 111200528);     // 256 KB

  const int NB1 = (M + 1023) / 1024;  // 98

  (void)hipMemsetAsync(cursor, 0, (size_t)M * sizeof(int), stream);
  prep_kernel<<<1024, 256, 0, stream>>>(W1, W1Tsw, er, ec, ev, cursor, cvps, E);
  scan1_kernel<<<NB1, 1024, 0, stream>>>(cursor, bsum, M);
  scan2_kernel<<<1, 64, 0, stream>>>(bsum, row_ptr, NB1, M);
  scan3_kernel<<<(M + 255) / 256, 256, 0, stream>>>(cursor, bsum, row_ptr, M);
  scatter_kernel<<<2048, 256, 0, stream>>>(er, cvps, cursor, cvp, E);
  gemm1_mfma<<<(M + 31) / 32, 256, 0, stream>>>(feat, W1Tsw, b1, h, M);
  spmm_fp8<<<(M + 3) / 4, 256, 0, stream>>>(row_ptr, cvp, h, hpost, M);
  gemm2_kernel<<<(M + 511) / 512, 256, 0, stream>>>(hpost, W2, b2, o, M);
  spmm_csr_40_lsm<<<(M + 3) / 4, 256, 0, stream>>>(row_ptr, cvp, o, out, M);
}

// Round 18
// 638.621 us; speedup vs baseline: 1.4551x; 1.0182x over previous
//
#include <hip/hip_runtime.h>
#include <hip/hip_bf16.h>
#include <math.h>

#define N_NODES 100000
#define N_FEAT 500
#define N_HID 256
#define N_CLASS 40
#define NT1 16  // gemm1 K-steps (512/32)

typedef float f32x4 __attribute__((ext_vector_type(4)));
typedef float f32x2 __attribute__((ext_vector_type(2)));
typedef int i32x4 __attribute__((ext_vector_type(4)));
typedef unsigned int u32x4 __attribute__((ext_vector_type(4)));
typedef short short8 __attribute__((ext_vector_type(8)));
typedef unsigned short u16x8 __attribute__((ext_vector_type(8)));

__device__ __forceinline__ float b2f(unsigned short u) {
  union { unsigned int i; float f; } c; c.i = ((unsigned int)u) << 16; return c.f;
}
__device__ __forceinline__ unsigned short f2bu(float x) {
  __hip_bfloat16 b = __float2bfloat16(x);
  union { __hip_bfloat16 b; unsigned short u; } c; c.b = b; return c.u;
}
__device__ __forceinline__ float decode_val(unsigned int p) {
  union { unsigned int i; float f; } c; c.i = (p & 0x7FFFu) << 17; return c.f;
}
__device__ __forceinline__ unsigned char f2fp8(float x) {
  return (unsigned char)(__builtin_amdgcn_cvt_pk_fp8_f32(x, x, 0, false) & 0xFF);
}
__device__ __forceinline__ void gload_lds16(const void* gptr, void* lptr) {
  __builtin_amdgcn_global_load_lds(
      (const __attribute__((address_space(1))) unsigned int*)gptr,
      (__attribute__((address_space(3))) unsigned int*)lptr, 16, 0, 0);
}

// ---------------------------------------------------------------------------
// prep: blocks 0..63 cast W1 -> W1Tsw bf16, transposed, padded, BK=32 chunk
// swizzle baked in: (col, s, c16) holds k = s*32 + (c16^(col&3))*8 ..+8.
// All blocks: histogram of er + pack cvps[i] = col<<15 | bf16(val)>>1.
// ---------------------------------------------------------------------------
__global__ __launch_bounds__(256) void prep_kernel(
    const float* __restrict__ W1, unsigned short* __restrict__ Bsw,
    const int* __restrict__ er, const int* __restrict__ ec,
    const float* __restrict__ ev, int* __restrict__ cnt,
    unsigned int* __restrict__ cvps, int E) {
  if (blockIdx.x < 64) {
    int t = blockIdx.x * 256 + threadIdx.x;  // 16384 = 256 cols x 16 s x 4 c16
    int col = t >> 6, rem = t & 63;
    int s = rem >> 2, c16 = rem & 3;
    int k_src = s * 32 + (c16 ^ (col & 3)) * 8;
    u16x8 o;
#pragma unroll
    for (int j = 0; j < 8; j++) {
      int kk = k_src + j;
      o[j] = (kk < N_FEAT) ? f2bu(W1[(size_t)kk * N_HID + col]) : (unsigned short)0;
    }
    *(u16x8*)(Bsw + (size_t)col * 512 + s * 32 + c16 * 8) = o;
  }
  int nv = E >> 2;
  int t = blockIdx.x * 256 + threadIdx.x;
  int nthr = gridDim.x * 256;
  const i32x4* er4 = (const i32x4*)er;
  const i32x4* ec4 = (const i32x4*)ec;
  const f32x4* ev4 = (const f32x4*)ev;
  for (int i = t; i < nv; i += nthr) {
    i32x4 r = __builtin_nontemporal_load(&er4[i]);
    i32x4 c = __builtin_nontemporal_load(&ec4[i]);
    f32x4 v = __builtin_nontemporal_load(&ev4[i]);
    atomicAdd(&cnt[r.x], 1);
    atomicAdd(&cnt[r.y], 1);
    atomicAdd(&cnt[r.z], 1);
    atomicAdd(&cnt[r.w], 1);
    u32x4 pk;
    pk.x = ((unsigned int)c.x << 15) | ((unsigned int)f2bu(v.x) >> 1);
    pk.y = ((unsigned int)c.y << 15) | ((unsigned int)f2bu(v.y) >> 1);
    pk.z = ((unsigned int)c.z << 15) | ((unsigned int)f2bu(v.z) >> 1);
    pk.w = ((unsigned int)c.w << 15) | ((unsigned int)f2bu(v.w) >> 1);
    __builtin_nontemporal_store(pk, (u32x4*)(cvps + 4 * (size_t)i));
  }
  int tail = nv << 2;
  if (blockIdx.x == 0 && threadIdx.x < E - tail) {
    int i = tail + threadIdx.x;
    atomicAdd(&cnt[er[i]], 1);
    cvps[i] = ((unsigned int)ec[i] << 15) | ((unsigned int)f2bu(ev[i]) >> 1);
  }
}

// ---------------------------------------------------------------------------
// GEMM1 (bf16 MFMA, double-buffered): H[M,256] = A[M,500] @ W1 + b1, fp8 out.
// BM=64, BN=256, BK=32, 16 K-steps; ALL staging via global_load_lds (A kept
// f32 in LDS, cvt after ds_read); 2-phase dbuf (48 KB -> 3 blk/CU): issue
// stage(t+1) BEFORE compute(t), one barrier per step.
// ---------------------------------------------------------------------------
__global__ __launch_bounds__(256) void gemm1_mfma(
    const float* __restrict__ A, const unsigned short* __restrict__ Bsw,
    const float* __restrict__ b1, unsigned char* __restrict__ H, int M) {
  __shared__ __align__(16) char smem[49152];  // sA[2][8K] @0, sB[2][16K] @16K
  int tid = threadIdx.x;
  int lane = tid & 63, w = tid >> 6;
  int wc = w;
  int bm = blockIdx.x * 64;

  f32x4 acc[4][4];
#pragma unroll
  for (int m = 0; m < 4; m++)
#pragma unroll
    for (int n = 0; n < 4; n++) acc[m][n] = (f32x4)0.f;

  auto stageA = [&](int buf, int s) {
    int k0 = s * 32;
    char* dst = smem + buf * 8192;
#pragma unroll
    for (int i = 0; i < 2; i++) {
      int base = i * 4096 + w * 1024;   // wave-uniform LDS dest
      int L = base + lane * 16;
      int row = L >> 7;                 // 128 B per row (32 f32)
      int c16 = (L >> 4) & 7;
      int c32 = c16 >> 1, sub = c16 & 1;
      int c32s = c32 ^ (row & 3);       // source pre-swizzle (inverse of read)
      int k = k0 + c32s * 8 + sub * 4;
      int grow = bm + row;
      const float* src = (grow < M && k < N_FEAT)
                             ? A + (size_t)grow * N_FEAT + k
                             : A;  // dummy: k>=500 hits zero B; rows>=M masked
      gload_lds16(src, dst + base);
    }
  };
  auto stageB = [&](int buf, int s) {
    char* dst = smem + 16384 + buf * 16384;
#pragma unroll
    for (int j = 0; j < 4; j++) {
      int base = j * 4096 + w * 1024;
      int L = base + lane * 16;
      int col = L >> 6;                 // 64 B per col (32 bf16)
      int c16 = (L >> 4) & 3;
      const char* g = (const char*)Bsw + (size_t)col * 1024 + s * 64 + c16 * 16;
      gload_lds16(g, dst + base);
    }
  };
  auto compute = [&](int buf) {
    const char* sA = smem + buf * 8192;
    const char* sB = smem + 16384 + buf * 16384;
    int cw = lane >> 4;       // k-slice 0..3
    int lr = lane & 15;
    short8 af[4], bg[4];
#pragma unroll
    for (int m = 0; m < 4; m++) {
      int ar = m * 16 + lr;
      const f32x4* p = (const f32x4*)(sA + ar * 128 + ((cw ^ (ar & 3)) << 5));
      f32x4 lo = p[0];
      f32x4 hi = p[1];
      u16x8 t;
      t[0] = f2bu(lo.x); t[1] = f2bu(lo.y); t[2] = f2bu(lo.z); t[3] = f2bu(lo.w);
      t[4] = f2bu(hi.x); t[5] = f2bu(hi.y); t[6] = f2bu(hi.z); t[7] = f2bu(hi.w);
      union { u16x8 u; short8 s; } cv; cv.u = t;
      af[m] = cv.s;
    }
#pragma unroll
    for (int n = 0; n < 4; n++) {
      int bc = wc * 64 + n * 16 + lr;
      bg[n] = *(const short8*)(sB + bc * 64 + ((cw ^ (bc & 3)) << 4));
    }
#pragma unroll
    for (int m = 0; m < 4; m++)
#pragma unroll
      for (int n = 0; n < 4; n++)
        acc[m][n] = __builtin_amdgcn_mfma_f32_16x16x32_bf16(af[m], bg[n], acc[m][n], 0, 0, 0);
  };

  stageA(0, 0);
  stageB(0, 0);
  __syncthreads();  // vmcnt(0) drain before barrier (compiler-inserted)
  int cur = 0;
  for (int s = 0; s < NT1 - 1; s++) {
    stageA(cur ^ 1, s + 1);   // issue next-tile async loads BEFORE compute
    stageB(cur ^ 1, s + 1);
    compute(cur);
    __syncthreads();          // drains next-tile loads; all waves done with cur
    cur ^= 1;
  }
  compute(cur);

  float bias[4];
#pragma unroll
  for (int n = 0; n < 4; n++) bias[n] = b1[wc * 64 + n * 16 + (lane & 15)];
#pragma unroll
  for (int m = 0; m < 4; m++) {
#pragma unroll
    for (int r = 0; r < 4; r++) {
      int row = bm + m * 16 + ((lane >> 4) << 2) + r;
      if (row < M) {
#pragma unroll
        for (int n = 0; n < 4; n++) {
          int col = wc * 64 + n * 16 + (lane & 15);
          H[(size_t)row * N_HID + col] = f2fp8(acc[m][n][r] + bias[n]);
        }
      }
    }
  }
}

// ---------------------------------------------------------------------------
// scans (unchanged)
// ---------------------------------------------------------------------------
__global__ __launch_bounds__(1024) void scan1_kernel(
    int* __restrict__ cnt, int* __restrict__ bsum, int n) {
  __shared__ int wsum[16];
  int tid = threadIdx.x, lane = tid & 63, wid = tid >> 6;
  int i = blockIdx.x * 1024 + tid;
  int v = (i < n) ? cnt[i] : 0;
  int x = v;
#pragma unroll
  for (int off = 1; off < 64; off <<= 1) {
    int t = __shfl_up(x, off);
    if (lane >= off) x += t;
  }
  if (lane == 63) wsum[wid] = x;
  __syncthreads();
  if (tid < 16) {
    int ws = wsum[tid];
#pragma unroll
    for (int off = 1; off < 16; off <<= 1) {
      int t = __shfl_up(ws, off);
      if (tid >= off) ws += t;
    }
    wsum[tid] = ws;
  }
  __syncthreads();
  int excl = (wid ? wsum[wid - 1] : 0) + x - v;
  if (i < n) cnt[i] = excl;
  if (tid == 0) bsum[blockIdx.x] = wsum[15];
}

__global__ __launch_bounds__(64) void scan2_kernel(
    int* __restrict__ bsum, int* __restrict__ row_ptr, int nb, int n) {
  int lane = threadIdx.x;
  int carry = 0;
  for (int base = 0; base < nb; base += 64) {
    int i = base + lane;
    int v = (i < nb) ? bsum[i] : 0;
    int x = v;
#pragma unroll
    for (int off = 1; off < 64; off <<= 1) {
      int t = __shfl_up(x, off);
      if (lane >= off) x += t;
    }
    if (i < nb) bsum[i] = carry + x - v;
    carry += __shfl(x, 63);
  }
  if (lane == 0) row_ptr[n] = carry;
}

__global__ __launch_bounds__(256) void scan3_kernel(
    int* __restrict__ cnt, const int* __restrict__ bsum,
    int* __restrict__ row_ptr, int n) {
  int i = blockIdx.x * 256 + threadIdx.x;
  if (i >= n) return;
  int v = cnt[i] + bsum[i >> 10];
  cnt[i] = v;
  row_ptr[i] = v;
}

// ---------------------------------------------------------------------------
// XCD-sliced scatter (r12 exact): 4 slices, plain stores.
// ---------------------------------------------------------------------------
__global__ __launch_bounds__(256) void scatter_kernel(
    const int* __restrict__ er, const unsigned int* __restrict__ cvps,
    int* __restrict__ cursor, unsigned int* __restrict__ cvp, int E) {
  int s = blockIdx.x & 3;
  int g = blockIdx.x >> 2;
  int ngrp = gridDim.x >> 2;
  int nv = E >> 2;
  const i32x4* er4 = (const i32x4*)er;
  const u32x4* cv4 = (const u32x4*)cvps;
  for (int i = g * 256 + threadIdx.x; i < nv; i += ngrp * 256) {
    i32x4 r = __builtin_nontemporal_load(&er4[i]);
    u32x4 p = __builtin_nontemporal_load(&cv4[i]);
    if (((r.x >> 9) & 3) == s) cvp[atomicAdd(&cursor[r.x], 1)] = p.x;
    if (((r.y >> 9) & 3) == s) cvp[atomicAdd(&cursor[r.y], 1)] = p.y;
    if (((r.z >> 9) & 3) == s) cvp[atomicAdd(&cursor[r.z], 1)] = p.z;
    if (((r.w >> 9) & 3) == s) cvp[atomicAdd(&cursor[r.w], 1)] = p.w;
  }
  int tail = nv << 2;
  if (blockIdx.x == 0 && threadIdx.x < E - tail) {
    int i = tail + threadIdx.x;
    cvp[atomicAdd(&cursor[er[i]], 1)] = cvps[i];
  }
}

// ---------------------------------------------------------------------------
// SPMM1 (CSR, F=256, fp8 X -> bf16 Y, fused ReLU): wave per row, 4 edges per
// step (16-lane groups), 16 feats x 16 B gather per lane, HW fp8 decode;
// cvp load pipelined one step ahead.
// ---------------------------------------------------------------------------
__global__ __launch_bounds__(256) void spmm_fp8(
    const int* __restrict__ row_ptr, const unsigned int* __restrict__ cvp,
    const unsigned char* __restrict__ X, unsigned short* __restrict__ Y, int M) {
  int wave = (blockIdx.x * 256 + threadIdx.x) >> 6;
  int lane = threadIdx.x & 63;
  if (wave >= M) return;
  int start = row_ptr[wave], end = row_ptr[wave + 1];
  int qf = lane >> 4, fl = lane & 15;
  f32x4 a0 = (f32x4)0.f, a1 = (f32x4)0.f, a2 = (f32x4)0.f, a3 = (f32x4)0.f;
  const unsigned char* Xf = X + fl * 16;
  unsigned int pcur;
  {
    int ei = start + qf;
    pcur = (ei < end) ? cvp[ei] : 0u;
  }
#pragma unroll 2
  for (int e = start; e < end; e += 4) {
    int en = e + 4 + qf;
    unsigned int pnext = (en < end) ? cvp[en] : 0u;
    float val = decode_val(pcur);
    size_t col = (size_t)(pcur >> 15);
    u32x4 d = *(const u32x4*)(Xf + col * N_HID);
    f32x2 f0 = __builtin_amdgcn_cvt_pk_f32_fp8(d.x, false);
    f32x2 f1 = __builtin_amdgcn_cvt_pk_f32_fp8(d.x, true);
    f32x2 f2 = __builtin_amdgcn_cvt_pk_f32_fp8(d.y, false);
    f32x2 f3 = __builtin_amdgcn_cvt_pk_f32_fp8(d.y, true);
    f32x2 f4 = __builtin_amdgcn_cvt_pk_f32_fp8(d.z, false);
    f32x2 f5 = __builtin_amdgcn_cvt_pk_f32_fp8(d.z, true);
    f32x2 f6 = __builtin_amdgcn_cvt_pk_f32_fp8(d.w, false);
    f32x2 f7 = __builtin_amdgcn_cvt_pk_f32_fp8(d.w, true);
    a0.x = fmaf(val, f0.x, a0.x); a0.y = fmaf(val, f0.y, a0.y);
    a0.z = fmaf(val, f1.x, a0.z); a0.w = fmaf(val, f1.y, a0.w);
    a1.x = fmaf(val, f2.x, a1.x); a1.y = fmaf(val, f2.y, a1.y);
    a1.z = fmaf(val, f3.x, a1.z); a1.w = fmaf(val, f3.y, a1.w);
    a2.x = fmaf(val, f4.x, a2.x); a2.y = fmaf(val, f4.y, a2.y);
    a2.z = fmaf(val, f5.x, a2.z); a2.w = fmaf(val, f5.y, a2.w);
    a3.x = fmaf(val, f6.x, a3.x); a3.y = fmaf(val, f6.y, a3.y);
    a3.z = fmaf(val, f7.x, a3.z); a3.w = fmaf(val, f7.y, a3.w);
    pcur = pnext;
  }
#define RED2(v) v += __shfl_xor(v, 16); v += __shfl_xor(v, 32);
  RED2(a0.x) RED2(a0.y) RED2(a0.z) RED2(a0.w)
  RED2(a1.x) RED2(a1.y) RED2(a1.z) RED2(a1.w)
  RED2(a2.x) RED2(a2.y) RED2(a2.z) RED2(a2.w)
  RED2(a3.x) RED2(a3.y) RED2(a3.z) RED2(a3.w)
#undef RED2
  if (qf == 0) {
    u16x8 o;
    o[0] = f2bu(fmaxf(a0.x, 0.f)); o[1] = f2bu(fmaxf(a0.y, 0.f));
    o[2] = f2bu(fmaxf(a0.z, 0.f)); o[3] = f2bu(fmaxf(a0.w, 0.f));
    o[4] = f2bu(fmaxf(a1.x, 0.f)); o[5] = f2bu(fmaxf(a1.y, 0.f));
    o[6] = f2bu(fmaxf(a1.z, 0.f)); o[7] = f2bu(fmaxf(a1.w, 0.f));
    *(u16x8*)(Y + (size_t)wave * N_HID + fl * 16) = o;
    o[0] = f2bu(fmaxf(a2.x, 0.f)); o[1] = f2bu(fmaxf(a2.y, 0.f));
    o[2] = f2bu(fmaxf(a2.z, 0.f)); o[3] = f2bu(fmaxf(a2.w, 0.f));
    o[4] = f2bu(fmaxf(a3.x, 0.f)); o[5] = f2bu(fmaxf(a3.y, 0.f));
    o[6] = f2bu(fmaxf(a3.z, 0.f)); o[7] = f2bu(fmaxf(a3.w, 0.f));
    *(u16x8*)(Y + (size_t)wave * N_HID + fl * 16 + 8) = o;
  }
}

// ---------------------------------------------------------------------------
// GEMM2: O[M,40](bf16) = Hpost[M,256](bf16) @ W2[256,40] + b2; 2 rows/thread.
// ---------------------------------------------------------------------------
__global__ __launch_bounds__(256) void gemm2_kernel(
    const unsigned short* __restrict__ H, const float* __restrict__ W2,
    const float* __restrict__ b2, unsigned short* __restrict__ O, int M) {
  __shared__ float Ws[N_HID * N_CLASS];
  __shared__ float sb2[N_CLASS];
  int tid = threadIdx.x;
  for (int i = tid; i < N_HID * N_CLASS; i += 256) Ws[i] = W2[i];
  if (tid < N_CLASS) sb2[tid] = b2[tid];
  __syncthreads();
  int r0 = (blockIdx.x * 256 + tid) * 2;
  if (r0 >= M) return;
  int r1 = r0 + 1;
  bool has1 = r1 < M;
  float acc0[N_CLASS], acc1[N_CLASS];
#pragma unroll
  for (int n = 0; n < N_CLASS; n++) { acc0[n] = sb2[n]; acc1[n] = sb2[n]; }
  const unsigned short* h0 = H + (size_t)r0 * N_HID;
  const unsigned short* h1 = H + (size_t)(has1 ? r1 : r0) * N_HID;
  for (int k0 = 0; k0 < N_HID; k0 += 8) {
    u16x8 va = *(const u16x8*)(h0 + k0);
    u16x8 vb = *(const u16x8*)(h1 + k0);
#pragma unroll
    for (int j = 0; j < 8; j++) {
      float a0 = b2f(va[j]), a1 = b2f(vb[j]);
      const float* wrow = &Ws[(k0 + j) * N_CLASS];
#pragma unroll
      for (int n = 0; n < N_CLASS; n++) {
        float wv = wrow[n];
        acc0[n] = fmaf(a0, wv, acc0[n]);
        acc1[n] = fmaf(a1, wv, acc1[n]);
      }
    }
  }
  unsigned short* o0 = O + (size_t)r0 * N_CLASS;
#pragma unroll
  for (int n = 0; n < N_CLASS; n += 4) {
    ushort4 p;
    p.x = f2bu(acc0[n]); p.y = f2bu(acc0[n + 1]);
    p.z = f2bu(acc0[n + 2]); p.w = f2bu(acc0[n + 3]);
    *(ushort4*)(o0 + n) = p;
  }
  if (has1) {
    unsigned short* o1 = O + (size_t)r1 * N_CLASS;
#pragma unroll
    for (int n = 0; n < N_CLASS; n += 4) {
      ushort4 p;
      p.x = f2bu(acc1[n]); p.y = f2bu(acc1[n + 1]);
      p.z = f2bu(acc1[n + 2]); p.w = f2bu(acc1[n + 3]);
      *(ushort4*)(o1 + n) = p;
    }
  }
}

// ---------------------------------------------------------------------------
// SPMM2 (F=40, bf16 X, packed cvp) + fused log_softmax: wave/row, unroll 4
// ---------------------------------------------------------------------------
__global__ __launch_bounds__(256) void spmm_csr_40_lsm(
    const int* __restrict__ row_ptr, const unsigned int* __restrict__ cvp,
    const unsigned short* __restrict__ X, float* __restrict__ Out, int M) {
  int wave = (blockIdx.x * 256 + threadIdx.x) >> 6;
  int lane = threadIdx.x & 63;
  if (wave >= M) return;
  int start = row_ptr[wave], end = row_ptr[wave + 1];
  bool act = lane < N_CLASS;
  int ln = act ? lane : 0;
  const unsigned short* Xc = X + ln;
  float acc = 0.f;
  int e = start;
  for (; e + 4 <= end; e += 4) {
    unsigned int p0 = cvp[e], p1 = cvp[e + 1], p2 = cvp[e + 2], p3 = cvp[e + 3];
    unsigned short x0 = Xc[(size_t)(p0 >> 15) * N_CLASS];
    unsigned short x1 = Xc[(size_t)(p1 >> 15) * N_CLASS];
    unsigned short x2 = Xc[(size_t)(p2 >> 15) * N_CLASS];
    unsigned short x3 = Xc[(size_t)(p3 >> 15) * N_CLASS];
    acc = fmaf(decode_val(p0), b2f(x0), acc);
    acc = fmaf(decode_val(p1), b2f(x1), acc);
    acc = fmaf(decode_val(p2), b2f(x2), acc);
    acc = fmaf(decode_val(p3), b2f(x3), acc);
  }
  for (; e < end; e++) {
    unsigned int p0 = cvp[e];
    acc = fmaf(decode_val(p0), b2f(Xc[(size_t)(p0 >> 15) * N_CLASS]), acc);
  }
  float mv = act ? acc : -INFINITY;
#pragma unroll
  for (int off = 32; off; off >>= 1) mv = fmaxf(mv, __shfl_xor(mv, off));
  float ex = act ? expf(acc - mv) : 0.f;
  float s = ex;
#pragma unroll
  for (int off = 32; off; off >>= 1) s += __shfl_xor(s, off);
  float lse = mv + logf(s);
  if (act) Out[(size_t)wave * N_CLASS + lane] = acc - lse;
}

// ---------------------------------------------------------------------------
extern "C" void kernel_launch(void* const* d_in, const int* in_sizes, int n_in,
                              void* d_out, int out_size, void* d_ws, size_t ws_size,
                              hipStream_t stream) {
  const float* feat = (const float*)d_in[0];
  const int* er     = (const int*)d_in[1];
  const int* ec     = (const int*)d_in[2];
  const float* ev   = (const float*)d_in[3];
  const float* W1   = (const float*)d_in[4];
  const float* b1   = (const float*)d_in[5];
  const float* W2   = (const float*)d_in[6];
  const float* b2   = (const float*)d_in[7];
  float* out = (float*)d_out;
  const int M = N_NODES;
  const int E = in_sizes[1];

  char* ws = (char*)d_ws;
  unsigned char* h      = (unsigned char*)(ws);                  // 25.6 MB fp8
  unsigned short* hpost = (unsigned short*)(ws + 25600000);      // 51.2 MB bf16
  unsigned short* o     = (unsigned short*)(ws + 76800000);      // 8 MB bf16
  int* row_ptr          = (int*)(ws + 84800000);                 // 400,004 B
  int* cursor           = (int*)(ws + 85200016);                 // 400,000 B
  int* bsum             = (int*)(ws + 85600016);                 // 512 B
  unsigned int* cvp     = (unsigned int*)(ws + 85600528);        // 12.8 MB
  unsigned int* cvps    = (unsigned int*)(ws + 98400528);        // 12.8 MB
  unsigned short* W1Tsw = (unsigned short*)(ws + 111200528);     // 256 KB

  const int NB1 = (M + 1023) / 1024;  // 98

  (void)hipMemsetAsync(cursor, 0, (size_t)M * sizeof(int), stream);
  prep_kernel<<<1024, 256, 0, stream>>>(W1, W1Tsw, er, ec, ev, cursor, cvps, E);
  scan1_kernel<<<NB1, 1024, 0, stream>>>(cursor, bsum, M);
  scan2_kernel<<<1, 64, 0, stream>>>(bsum, row_ptr, NB1, M);
  scan3_kernel<<<(M + 255) / 256, 256, 0, stream>>>(cursor, bsum, row_ptr, M);
  scatter_kernel<<<2048, 256, 0, stream>>>(er, cvps, cursor, cvp, E);
  gemm1_mfma<<<(M + 63) / 64, 256, 0, stream>>>(feat, W1Tsw, b1, h, M);
  spmm_fp8<<<(M + 3) / 4, 256, 0, stream>>>(row_ptr, cvp, h, hpost, M);
  gemm2_kernel<<<(M + 511) / 512, 256, 0, stream>>>(hpost, W2, b2, o, M);
  spmm_csr_40_lsm<<<(M + 3) / 4, 256, 0, stream>>>(row_ptr, cvp, o, out, M);
}